// Round 6
// baseline (816.425 us; speedup 1.0000x reference)
//
#include <hip/hip_runtime.h>
#include <hip/hip_bf16.h>

// CGCNN forward, recompute-t + swapped-operand MFMA:
//   t[n,m,:] = hi[n,:] + hj[idx[n,m],:] + bond[n,m,:]@w_b   (bias folded into hi)
// mfma(wb_frag, bond_frag, acc) -> D^T: lane owns ONE bond, 4 consecutive t-cols/reg
//   -> hi/hj gathers are ushort4 (8B) instead of scalar 2B; filt/core pair in-thread.
// bn1 mean analytic (linearity): S_bf@wb + 12*colsum(hi) + cnt-weighted colsum(hj);
// only E[t^2] measured in k_stat (sq-only -> 32 stat VGPRs, wbT LDS-resident).
// k_fuse: 192 thr / 48-bond tiles (4 aligned sites) -> in-register gate, LDS m-reduce.

#define NN 40000
#define MM 12
#define AA 64
#define LL 3
#define CC 128
#define F0C 92
#define NBOND (NN*MM)
#define EPSBN 1e-5f

#define G_STAT 1024
#define NT_STAT 7500     // 64-bond tiles
#define G_FUSE 1024
#define NT_FUSE 10000    // 48-bond tiles
#define G_PROJ 1250

#define L2E 1.4426950408889634f
#define LN2 0.6931471805599453f

typedef __attribute__((ext_vector_type(8))) short bf16x8;
typedef __attribute__((ext_vector_type(4))) float f32x4;

__device__ __forceinline__ float softplusf_(float x) {
    float e = __builtin_amdgcn_exp2f(-fabsf(x) * L2E);
    return fmaxf(x, 0.f) + __builtin_amdgcn_logf(1.f + e) * LN2;
}
__device__ __forceinline__ float sigmoidf_(float x) {
    return __builtin_amdgcn_rcpf(1.f + __builtin_amdgcn_exp2f(-x * L2E));
}
__device__ __forceinline__ unsigned short f2bf(float f) {
    unsigned int u = __float_as_uint(f);
    unsigned int r = (u + 0x7fffu + ((u >> 16) & 1u)) >> 16;
    return (unsigned short)r;
}
__device__ __forceinline__ float bf2f(unsigned short s) {
    return __uint_as_float(((unsigned int)s) << 16);
}

// ---------------- bond features f32 -> bf16, once ----------------
__global__ __launch_bounds__(256) void k_cvt(const float* __restrict__ in,
        unsigned short* __restrict__ out) {
    size_t i = ((size_t)blockIdx.x * 256 + threadIdx.x) * 8;
    float4 a = *(const float4*)&in[i];
    float4 b = *(const float4*)&in[i + 4];
    ushort4 ua, ub;
    ua.x = f2bf(a.x); ua.y = f2bf(a.y); ua.z = f2bf(a.z); ua.w = f2bf(a.w);
    ub.x = f2bf(b.x); ub.y = f2bf(b.y); ub.z = f2bf(b.z); ub.w = f2bf(b.w);
    *(ushort4*)&out[i] = ua;
    *(ushort4*)&out[i + 4] = ub;
}

// ---------------- cnt histogram (once; int atomics = deterministic) ----------------
__global__ __launch_bounds__(256) void k_zero(int* __restrict__ cnt) {
    int i = blockIdx.x * 256 + threadIdx.x;
    if (i < NN) cnt[i] = 0;
}
__global__ __launch_bounds__(256) void k_cnt(const int* __restrict__ bidx,
        int* __restrict__ cnt) {
    int i = blockIdx.x * 256 + threadIdx.x;
    if (i < NBOND) atomicAdd(&cnt[bidx[i]], 1);
}

// ---------------- S_bf = colsum of (bf16-rounded) bond features, once ----------------
template<bool BFQ>
__global__ __launch_bounds__(256) void k_sbf(const float* __restrict__ bf,
        const unsigned short* __restrict__ bfq, float* __restrict__ part) {
    __shared__ float red[4][64];
    int tid = threadIdx.x, c = tid & 63, rg = tid >> 6;
    size_t base = (size_t)blockIdx.x * 1875;
    float acc = 0.f;
    for (int r = rg; r < 1875; r += 4) {
        if constexpr (BFQ) acc += bf2f(bfq[(base + r) * 64 + c]);
        else               acc += bf2f(f2bf(bf[(base + r) * 64 + c]));
    }
    red[rg][c] = acc;
    __syncthreads();
    if (tid < 64) part[(size_t)blockIdx.x * 64 + tid]
        = red[0][tid] + red[1][tid] + red[2][tid] + red[3][tid];
}
__global__ __launch_bounds__(64) void k_sbf2(const float* __restrict__ part,
        float* __restrict__ sbf) {
    int tid = threadIdx.x;
    float a = 0.f;
    for (int b = 0; b < 256; ++b) a += part[(size_t)b * 64 + tid];
    sbf[tid] = a;
}

// ---------------- fc1 ----------------
__global__ __launch_bounds__(256) void k_fc1(const float* __restrict__ site,
        const float* __restrict__ w, const float* __restrict__ b,
        float* __restrict__ h) {
    __shared__ float w_s[F0C][AA];
    __shared__ float x_s[16][F0C];
    int tid = threadIdx.x;
    for (int i = tid; i < F0C * AA; i += 256) w_s[i / AA][i % AA] = w[i];
    int n0 = blockIdx.x * 16;
    for (int i = tid; i < 16 * F0C; i += 256) x_s[i / F0C][i % F0C] = site[(size_t)n0 * F0C + i];
    __syncthreads();
    int d = tid & 63, ng = tid >> 6;
    float bb = b[d];
    float acc[4] = {bb, bb, bb, bb};
    #pragma unroll 4
    for (int k = 0; k < F0C; ++k) {
        float wv = w_s[k][d];
        acc[0] += x_s[ng][k] * wv;
        acc[1] += x_s[ng + 4][k] * wv;
        acc[2] += x_s[ng + 8][k] * wv;
        acc[3] += x_s[ng + 12][k] * wv;
    }
    #pragma unroll
    for (int rr = 0; rr < 4; ++rr)
        h[(size_t)(n0 + ng + rr * 4) * AA + d] = acc[rr];
}

// ---------------- proj: hi/hj bf16 + colsum partials (hi plain, hj cnt-weighted) ----------------
__global__ __launch_bounds__(256) void k_proj(const float* __restrict__ h,
        const float* __restrict__ convw, const float* __restrict__ convb,
        const int* __restrict__ cnt,
        unsigned short* __restrict__ hi, unsigned short* __restrict__ hj,
        float* __restrict__ partP) {
    __shared__ float w_s[64][256];
    __shared__ float hT[64][36];
    int tid = threadIdx.x;
    for (int i = tid; i < 64 * 256; i += 256) {
        int k = i >> 8, c = i & 255;
        w_s[k][c] = convw[(size_t)((c < 128 ? k : 64 + k)) * 128 + (c & 127)];
    }
    int row0 = blockIdx.x * 32;
    for (int i = tid; i < 2048; i += 256) {
        int r = i >> 6, k = i & 63;
        hT[k][r] = h[(size_t)(row0 + r) * 64 + k];
    }
    __syncthreads();
    int c0 = (tid & 63) * 4;          // abs col in 0..255 (hi: 0..127, hj: 128..255)
    int r0 = (tid >> 6) * 8;
    float acc[8][4];
    #pragma unroll
    for (int r = 0; r < 8; ++r)
        #pragma unroll
        for (int i = 0; i < 4; ++i) acc[r][i] = 0.f;
    #pragma unroll 4
    for (int k = 0; k < 64; ++k) {
        float4 w4 = *(const float4*)&w_s[k][c0];
        float4 ha = *(const float4*)&hT[k][r0];
        float4 hb = *(const float4*)&hT[k][r0 + 4];
        float wv[4] = {w4.x, w4.y, w4.z, w4.w};
        float hv[8] = {ha.x, ha.y, ha.z, ha.w, hb.x, hb.y, hb.z, hb.w};
        #pragma unroll
        for (int r = 0; r < 8; ++r)
            #pragma unroll
            for (int i = 0; i < 4; ++i) acc[r][i] += hv[r] * wv[i];
    }
    bool isHi = (c0 < 128);
    int cc = isHi ? c0 : c0 - 128;
    float4 cb4 = make_float4(0.f, 0.f, 0.f, 0.f);
    if (isHi) cb4 = *(const float4*)&convb[c0];
    unsigned short* dst = isHi ? hi : hj;
    float psum[4] = {0.f, 0.f, 0.f, 0.f};
    #pragma unroll
    for (int r = 0; r < 8; ++r) {
        int n = row0 + r0 + r;
        ushort4 o;
        o.x = f2bf(acc[r][0] + cb4.x);
        o.y = f2bf(acc[r][1] + cb4.y);
        o.z = f2bf(acc[r][2] + cb4.z);
        o.w = f2bf(acc[r][3] + cb4.w);
        *(ushort4*)&dst[(size_t)n * 128 + cc] = o;
        float wt = isHi ? 1.f : (float)cnt[n];
        psum[0] += wt * bf2f(o.x);
        psum[1] += wt * bf2f(o.y);
        psum[2] += wt * bf2f(o.z);
        psum[3] += wt * bf2f(o.w);
    }
    __syncthreads();                 // w_s dead -> overlay reduction buffer
    float* redp = &w_s[0][0];        // [4][256]
    int rg = tid >> 6;
    #pragma unroll
    for (int i = 0; i < 4; ++i) redp[rg * 256 + c0 + i] = psum[i];
    __syncthreads();
    partP[(size_t)blockIdx.x * 256 + tid] =
        redp[tid] + redp[256 + tid] + redp[512 + tid] + redp[768 + tid];
}

// ---------------- pass 1: E[t^2] partials (swapped-operand MFMA) ----------------
template<bool BFQ>
__global__ __launch_bounds__(256) void k_stat(const float* __restrict__ bf,
        const unsigned short* __restrict__ bfq,
        const float* __restrict__ wb,
        const unsigned short* __restrict__ hi, const unsigned short* __restrict__ hj,
        const int* __restrict__ bidx,
        float* __restrict__ partS) {
    __shared__ unsigned short wbT[128][72];   // resident: [col][k] bf16
    __shared__ unsigned short A_lds[64][72];  // [bond][k] bf16
    __shared__ float red[4][128];

    int tid = threadIdx.x;
    int lane = tid & 63, w = tid >> 6;
    int l15 = lane & 15, l4 = lane >> 4;

    for (int i = tid; i < 64 * 128; i += 256) {
        int k = i >> 7, c = i & 127;
        wbT[c][k] = f2bf(wb[i]);
    }

    float sql[8][4];
    #pragma unroll
    for (int ct = 0; ct < 8; ++ct)
        #pragma unroll
        for (int r = 0; r < 4; ++r) sql[ct][r] = 0.f;

    int myb = w * 16 + l15;   // this thread's bond within the 64-bond tile
    for (int tile = blockIdx.x; tile < NT_STAT; tile += G_STAT) {
        int bond0 = tile * 64;
        __syncthreads();
        // stage A: 64 bonds x 64 k (512 8-elem chunks / 256 threads)
        #pragma unroll
        for (int ii = 0; ii < 2; ++ii) {
            int idx = tid + ii * 256;
            int r = idx >> 3, k8 = (idx & 7) * 8;
            if constexpr (BFQ) {
                bf16x8 v = *(const bf16x8*)&bfq[((size_t)(bond0 + r)) * 64 + k8];
                *(bf16x8*)&A_lds[r][k8] = v;
            } else {
                float4 v0 = *(const float4*)&bf[((size_t)(bond0 + r)) * 64 + k8];
                float4 v1 = *(const float4*)&bf[((size_t)(bond0 + r)) * 64 + k8 + 4];
                ushort4 ua, ub;
                ua.x = f2bf(v0.x); ua.y = f2bf(v0.y); ua.z = f2bf(v0.z); ua.w = f2bf(v0.w);
                ub.x = f2bf(v1.x); ub.y = f2bf(v1.y); ub.z = f2bf(v1.z); ub.w = f2bf(v1.w);
                *(ushort4*)&A_lds[r][k8] = ua;
                *(ushort4*)&A_lds[r][k8 + 4] = ub;
            }
        }
        __syncthreads();

        f32x4 acc[8];
        #pragma unroll
        for (int ct = 0; ct < 8; ++ct) acc[ct] = (f32x4){0.f, 0.f, 0.f, 0.f};
        #pragma unroll
        for (int kh = 0; kh < 2; ++kh) {
            bf16x8 a = *(const bf16x8*)&A_lds[myb][kh * 32 + l4 * 8];
            #pragma unroll
            for (int ct = 0; ct < 8; ++ct) {
                bf16x8 wf = *(const bf16x8*)&wbT[ct * 16 + l15][kh * 32 + l4 * 8];
                acc[ct] = __builtin_amdgcn_mfma_f32_16x16x32_bf16(wf, a, acc[ct], 0, 0, 0);
            }
        }

        int bond = bond0 + myb;
        int n = bond / MM;
        int j = bidx[bond];
        const unsigned short* hin = hi + (size_t)n * 128;
        const unsigned short* hjn = hj + (size_t)j * 128;
        #pragma unroll
        for (int ct = 0; ct < 8; ++ct) {
            int c0 = ct * 16 + l4 * 4;
            ushort4 h4 = *(const ushort4*)&hin[c0];
            ushort4 j4 = *(const ushort4*)&hjn[c0];
            float hh[4] = {bf2f(h4.x), bf2f(h4.y), bf2f(h4.z), bf2f(h4.w)};
            float jj[4] = {bf2f(j4.x), bf2f(j4.y), bf2f(j4.z), bf2f(j4.w)};
            #pragma unroll
            for (int r = 0; r < 4; ++r) {
                float t = acc[ct][r] + hh[r] + jj[r];
                sql[ct][r] += t * t;
            }
        }
    }

    // reduce sq over the 16 l15-lanes (bonds), then across waves via LDS
    #pragma unroll
    for (int ct = 0; ct < 8; ++ct)
        #pragma unroll
        for (int r = 0; r < 4; ++r) {
            float q = sql[ct][r];
            q += __shfl_xor(q, 1); q += __shfl_xor(q, 2);
            q += __shfl_xor(q, 4); q += __shfl_xor(q, 8);
            sql[ct][r] = q;
        }
    if (l15 == 0) {
        #pragma unroll
        for (int ct = 0; ct < 8; ++ct)
            #pragma unroll
            for (int r = 0; r < 4; ++r)
                red[w][ct * 16 + l4 * 4 + r] = sql[ct][r];
    }
    __syncthreads();
    if (tid < 128)
        partS[(size_t)blockIdx.x * 128 + tid] =
            red[0][tid] + red[1][tid] + red[2][tid] + red[3][tid];
}

// ---------------- generic width-preserving row reduction ----------------
__global__ void k_redw(const float* __restrict__ in, float* __restrict__ out,
                       int rows, int rper) {
    int tid = threadIdx.x, b = blockIdx.x, W = blockDim.x;
    float a = 0.f;
    int r0 = b * rper, r1 = r0 + rper;
    for (int r = r0; r < r1 && r < rows; ++r) a += in[(size_t)r * W + tid];
    out[(size_t)b * W + tid] = a;
}

// ---------------- finalize bn1: analytic mean + measured E[t^2] ----------------
__global__ __launch_bounds__(128) void k_fin1(const float* __restrict__ partSA,  // [128][128]
        const float* __restrict__ partPA,  // [125][256]
        const float* __restrict__ sbf,     // [64]
        const float* __restrict__ wb,      // [64][128] f32 (bond block)
        const float* __restrict__ g, const float* __restrict__ b,
        float* __restrict__ scsh) {
    int c = threadIdx.x;
    float sq = 0.f;
    for (int r = 0; r < 128; ++r) sq += partSA[(size_t)r * 128 + c];
    float his = 0.f, hjw = 0.f;
    for (int r = 0; r < 125; ++r) {
        his += partPA[(size_t)r * 256 + c];
        hjw += partPA[(size_t)r * 256 + 128 + c];
    }
    float sw = 0.f;
    for (int k = 0; k < 64; ++k) sw += sbf[k] * bf2f(f2bf(wb[(size_t)k * 128 + c]));
    float mean = (sw + 12.f * his + hjw) * (1.f / (float)NBOND);
    float var = sq * (1.f / (float)NBOND) - mean * mean;
    float sc = g[c] * rsqrtf(var + EPSBN);
    scsh[c] = sc;
    scsh[128 + c] = b[c] - mean * sc;
}

// ---------------- pass 2: recompute t, in-register gate, LDS m-reduce ----------------
template<bool BFQ>
__global__ __launch_bounds__(192) void k_fuse(const float* __restrict__ bf,
        const unsigned short* __restrict__ bfq,
        const float* __restrict__ wb,
        const unsigned short* __restrict__ hi, const unsigned short* __restrict__ hj,
        const int* __restrict__ bidx,
        const float* __restrict__ scsh,
        float* __restrict__ s_out,
        float* __restrict__ part2) {
    __shared__ unsigned short wbT[128][72];   // resident
    __shared__ unsigned short A_lds[48][72];
    __shared__ unsigned short val[48][68];    // gated values, 48 bonds x 64 cols
    __shared__ float red2[4][64];

    int tid = threadIdx.x;
    int lane = tid & 63, w = tid >> 6;        // w in 0..2
    int l15 = lane & 15, l4 = lane >> 4;

    for (int i = tid; i < 64 * 128; i += 192) {
        int k = i >> 7, c = i & 127;
        wbT[c][k] = f2bf(wb[i]);
    }

    // bn1 consts for this thread's 16 filt cols (+ core partners), hoisted to regs
    float scf[4][4], shf[4][4], scc[4][4], shc[4][4];
    #pragma unroll
    for (int ct = 0; ct < 4; ++ct)
        #pragma unroll
        for (int r = 0; r < 4; ++r) {
            int cf = ct * 16 + l4 * 4 + r;
            scf[ct][r] = scsh[cf];       shf[ct][r] = scsh[128 + cf];
            scc[ct][r] = scsh[64 + cf];  shc[ct][r] = scsh[192 + cf];
        }

    float sum2[4] = {0, 0, 0, 0}, sq2[4] = {0, 0, 0, 0};
    int myb = w * 16 + l15;   // bond within the 48-bond tile
    __syncthreads();          // wbT ready

    for (int tile = blockIdx.x; tile < NT_FUSE; tile += G_FUSE) {
        int bond0 = tile * 48;
        // stage A: 48 x 64 (384 chunks / 192 threads)
        #pragma unroll
        for (int ii = 0; ii < 2; ++ii) {
            int idx = tid + ii * 192;
            int r = idx >> 3, k8 = (idx & 7) * 8;
            if constexpr (BFQ) {
                bf16x8 v = *(const bf16x8*)&bfq[((size_t)(bond0 + r)) * 64 + k8];
                *(bf16x8*)&A_lds[r][k8] = v;
            } else {
                float4 v0 = *(const float4*)&bf[((size_t)(bond0 + r)) * 64 + k8];
                float4 v1 = *(const float4*)&bf[((size_t)(bond0 + r)) * 64 + k8 + 4];
                ushort4 ua, ub;
                ua.x = f2bf(v0.x); ua.y = f2bf(v0.y); ua.z = f2bf(v0.z); ua.w = f2bf(v0.w);
                ub.x = f2bf(v1.x); ub.y = f2bf(v1.y); ub.z = f2bf(v1.z); ub.w = f2bf(v1.w);
                *(ushort4*)&A_lds[r][k8] = ua;
                *(ushort4*)&A_lds[r][k8 + 4] = ub;
            }
        }
        __syncthreads();

        f32x4 acc[8];
        #pragma unroll
        for (int ct = 0; ct < 8; ++ct) acc[ct] = (f32x4){0.f, 0.f, 0.f, 0.f};
        #pragma unroll
        for (int kh = 0; kh < 2; ++kh) {
            bf16x8 a = *(const bf16x8*)&A_lds[myb][kh * 32 + l4 * 8];
            #pragma unroll
            for (int ct = 0; ct < 8; ++ct) {
                bf16x8 wf = *(const bf16x8*)&wbT[ct * 16 + l15][kh * 32 + l4 * 8];
                acc[ct] = __builtin_amdgcn_mfma_f32_16x16x32_bf16(wf, a, acc[ct], 0, 0, 0);
            }
        }

        int bond = bond0 + myb;
        int n = bond / MM;
        int j = bidx[bond];
        const unsigned short* hin = hi + (size_t)n * 128;
        const unsigned short* hjn = hj + (size_t)j * 128;
        #pragma unroll
        for (int ct = 0; ct < 4; ++ct) {
            int c0 = ct * 16 + l4 * 4;
            ushort4 hf = *(const ushort4*)&hin[c0];
            ushort4 jf = *(const ushort4*)&hjn[c0];
            ushort4 hc = *(const ushort4*)&hin[c0 + 64];
            ushort4 jc = *(const ushort4*)&hjn[c0 + 64];
            float hfv[4] = {bf2f(hf.x), bf2f(hf.y), bf2f(hf.z), bf2f(hf.w)};
            float jfv[4] = {bf2f(jf.x), bf2f(jf.y), bf2f(jf.z), bf2f(jf.w)};
            float hcv[4] = {bf2f(hc.x), bf2f(hc.y), bf2f(hc.z), bf2f(hc.w)};
            float jcv[4] = {bf2f(jc.x), bf2f(jc.y), bf2f(jc.z), bf2f(jc.w)};
            ushort4 o;
            unsigned short ov[4];
            #pragma unroll
            for (int r = 0; r < 4; ++r) {
                float tA = acc[ct][r] + hfv[r] + jfv[r];
                float tC = acc[ct + 4][r] + hcv[r] + jcv[r];
                float v = sigmoidf_(scf[ct][r] * tA + shf[ct][r])
                        * softplusf_(scc[ct][r] * tC + shc[ct][r]);
                ov[r] = f2bf(v);
            }
            o.x = ov[0]; o.y = ov[1]; o.z = ov[2]; o.w = ov[3];
            *(ushort4*)&val[myb][c0] = o;
        }
        __syncthreads();

        // m-reduce: 4 sites x 16 col-quads on the first 64 threads
        if (tid < 64) {
            int site = tid >> 4, q = tid & 15;
            float sv[4] = {0, 0, 0, 0};
            #pragma unroll
            for (int m = 0; m < MM; ++m) {
                ushort4 u = *(const ushort4*)&val[site * MM + m][q * 4];
                sv[0] += bf2f(u.x); sv[1] += bf2f(u.y);
                sv[2] += bf2f(u.z); sv[3] += bf2f(u.w);
            }
            int gsite = tile * 4 + site;
            *(float4*)&s_out[(size_t)gsite * 64 + q * 4] =
                make_float4(sv[0], sv[1], sv[2], sv[3]);
            #pragma unroll
            for (int i = 0; i < 4; ++i) { sum2[i] += sv[i]; sq2[i] += sv[i] * sv[i]; }
        }
        __syncthreads();   // val/A_lds consumed before next tile overwrites
    }

    // bn2 partials
    if (tid < 64) {
        int site = tid >> 4, q = tid & 15;
        #pragma unroll
        for (int i = 0; i < 4; ++i) red2[site][q * 4 + i] = sum2[i];
    }
    __syncthreads();
    if (tid < 64)
        part2[(size_t)blockIdx.x * 128 + tid] =
            red2[0][tid] + red2[1][tid] + red2[2][tid] + red2[3][tid];
    __syncthreads();
    if (tid < 64) {
        int site = tid >> 4, q = tid & 15;
        #pragma unroll
        for (int i = 0; i < 4; ++i) red2[site][q * 4 + i] = sq2[i];
    }
    __syncthreads();
    if (tid < 64)
        part2[(size_t)blockIdx.x * 128 + 64 + tid] =
            red2[0][tid] + red2[1][tid] + red2[2][tid] + red2[3][tid];
}

// ---------------- finalize bn2 ----------------
__global__ __launch_bounds__(128) void k_fin2(const float* __restrict__ partB,  // [128][128]
        const float* __restrict__ g, const float* __restrict__ b,
        float* __restrict__ scsh2) {
    __shared__ float sm[128];
    int tid = threadIdx.x;
    float acc = 0.f;
    for (int r = 0; r < 128; ++r) acc += partB[(size_t)r * 128 + tid];
    sm[tid] = acc;
    __syncthreads();
    if (tid < 64) {
        float m = sm[tid] / (float)NN;
        float v = sm[64 + tid] / (float)NN - m * m;
        float sc = g[tid] * rsqrtf(v + EPSBN);
        scsh2[tid] = sc;
        scsh2[64 + tid] = b[tid] - m * sc;
    }
}

// ---------------- h = softplus(h + bn2(s)) ----------------
__global__ __launch_bounds__(256) void k_upd(float* __restrict__ h, const float* __restrict__ s,
        const float* __restrict__ scsh2) {
    size_t i = ((size_t)blockIdx.x * 256 + threadIdx.x) * 4;
    int c0 = (int)(i & 63);
    float4 hv = *(const float4*)&h[i];
    float4 sv = *(const float4*)&s[i];
    float4 o;
    o.x = softplusf_(hv.x + scsh2[c0 + 0] * sv.x + scsh2[64 + c0 + 0]);
    o.y = softplusf_(hv.y + scsh2[c0 + 1] * sv.y + scsh2[64 + c0 + 1]);
    o.z = softplusf_(hv.z + scsh2[c0 + 2] * sv.z + scsh2[64 + c0 + 2]);
    o.w = softplusf_(hv.w + scsh2[c0 + 3] * sv.w + scsh2[64 + c0 + 3]);
    *(float4*)&h[i] = o;
}

// ---------------- pooling ----------------
__device__ __forceinline__ int lbound(const int* a, int n, int v) {
    int lo = 0, hi = n;
    while (lo < hi) { int mid = (lo + hi) >> 1; if (a[mid] < v) lo = mid + 1; else hi = mid; }
    return lo;
}

__global__ __launch_bounds__(256) void k_pool(const float* __restrict__ h,
        const int* __restrict__ cidx, float* __restrict__ feats) {
    __shared__ float red[4][68];
    __shared__ int bounds[2];
    int c = blockIdx.x, tid = threadIdx.x;
    if (tid == 0) {
        bounds[0] = lbound(cidx, NN, c);
        bounds[1] = lbound(cidx, NN, c + 1);
    }
    __syncthreads();
    int lo = bounds[0], hi = bounds[1];
    int d = tid & 63, g = tid >> 6;
    float acc = 0;
    for (int n = lo + g; n < hi; n += 4) acc += h[(size_t)n * 64 + d];
    red[g][d] = acc;
    __syncthreads();
    if (tid < 64) {
        float t = red[0][tid] + red[1][tid] + red[2][tid] + red[3][tid];
        int cnt = hi - lo;
        feats[(size_t)c * 65 + tid] = t / (float)(cnt > 0 ? cnt : 1);
    }
}

// ---------------- head ----------------
__global__ __launch_bounds__(128) void k_head1(float* __restrict__ feats, const float* __restrict__ fap,
        const float* __restrict__ g, const float* __restrict__ b, float* __restrict__ featsp) {
    int tid = threadIdx.x;
    if (tid < CC) feats[(size_t)tid * 65 + 64] = fap[tid];
    __syncthreads();
    if (tid < 65) {
        float s = 0;
        for (int r = 0; r < CC; ++r) s += feats[r * 65 + tid];
        float m = s / (float)CC;
        float v = 0;
        for (int r = 0; r < CC; ++r) { float d = feats[r * 65 + tid] - m; v += d * d; }
        v /= (float)CC;
        float sc = g[tid] * rsqrtf(v + EPSBN);
        float sh = b[tid] - m * sc;
        for (int r = 0; r < CC; ++r)
            featsp[r * 65 + tid] = softplusf_(sc * feats[r * 65 + tid] + sh);
    }
}

__global__ __launch_bounds__(128) void k_head2(const float* __restrict__ featsp,
        const float* __restrict__ fc2w, const float* __restrict__ fc2b,
        const float* __restrict__ fc3w, const float* __restrict__ fc3b,
        float* __restrict__ out) {
    __shared__ float fr[65];
    __shared__ float red[128];
    int r = blockIdx.x, tid = threadIdx.x;
    if (tid < 65) fr[tid] = featsp[(size_t)r * 65 + tid];
    __syncthreads();
    float acc = fc2b[tid];
    for (int k = 0; k < 65; ++k) acc += fr[k] * fc2w[k * 128 + tid];
    red[tid] = softplusf_(acc) * fc3w[tid];
    __syncthreads();
    for (int st = 64; st > 0; st >>= 1) {
        if (tid < st) red[tid] += red[tid + st];
        __syncthreads();
    }
    if (tid == 0) out[r] = red[0] + fc3b[0];
}

extern "C" void kernel_launch(void* const* d_in, const int* in_sizes, int n_in,
                              void* d_out, int out_size, void* d_ws, size_t ws_size,
                              hipStream_t stream) {
    const float* site  = (const float*)d_in[0];
    const float* bondf = (const float*)d_in[1];
    const float* fap   = (const float*)d_in[2];
    const float* fc1w  = (const float*)d_in[3];
    const float* fc1b  = (const float*)d_in[4];
    const float* convw = (const float*)d_in[5];
    const float* convb = (const float*)d_in[6];
    const float* bn1g  = (const float*)d_in[7];
    const float* bn1b  = (const float*)d_in[8];
    const float* bn2g  = (const float*)d_in[9];
    const float* bn2b  = (const float*)d_in[10];
    const float* topg  = (const float*)d_in[11];
    const float* topb  = (const float*)d_in[12];
    const float* fc2w  = (const float*)d_in[13];
    const float* fc2b  = (const float*)d_in[14];
    const float* fc3w  = (const float*)d_in[15];
    const float* fc3b  = (const float*)d_in[16];
    const int*   bidx  = (const int*)d_in[17];
    const int*   cidx  = (const int*)d_in[18];
    float* out = (float*)d_out;

    char* w = (char*)d_ws;
    constexpr size_t SZ_H   = (size_t)NN * 64 * 4;
    constexpr size_t SZ_HP  = (size_t)NN * 128 * 2;
    constexpr size_t OFF_H     = 0;
    constexpr size_t OFF_HI    = OFF_H + SZ_H;
    constexpr size_t OFF_HJ    = OFF_HI + SZ_HP;
    constexpr size_t OFF_S     = OFF_HJ + SZ_HP;
    constexpr size_t OFF_SCSH1 = OFF_S + SZ_H;
    constexpr size_t OFF_SCSH2 = OFF_SCSH1 + 1024;
    constexpr size_t OFF_PS    = OFF_SCSH2 + 512;
    constexpr size_t OFF_PSA   = OFF_PS + (size_t)G_STAT * 128 * 4;
    constexpr size_t OFF_PP    = OFF_PSA + (size_t)128 * 128 * 4;
    constexpr size_t OFF_PPA   = OFF_PP + (size_t)G_PROJ * 256 * 4;
    constexpr size_t OFF_P2    = OFF_PPA + (size_t)125 * 256 * 4;
    constexpr size_t OFF_P2A   = OFF_P2 + (size_t)G_FUSE * 128 * 4;
    constexpr size_t OFF_FE    = OFF_P2A + (size_t)128 * 128 * 4;
    constexpr size_t OFF_FP    = OFF_FE + 128 * 65 * 4;
    constexpr size_t OFF_CNT   = OFF_FP + 128 * 65 * 4;
    constexpr size_t OFF_SBP   = OFF_CNT + (size_t)NN * 4;
    constexpr size_t OFF_SBF   = OFF_SBP + (size_t)256 * 64 * 4;
    constexpr size_t OFF_BFQ   = ((OFF_SBF + 64 * 4) + 255) & ~(size_t)255;
    constexpr size_t NEED_BFQ  = OFF_BFQ + (size_t)NBOND * 64 * 2;

    float* h      = (float*)(w + OFF_H);
    unsigned short* hi = (unsigned short*)(w + OFF_HI);
    unsigned short* hj = (unsigned short*)(w + OFF_HJ);
    float* sbuf   = (float*)(w + OFF_S);
    float* scsh1  = (float*)(w + OFF_SCSH1);
    float* scsh2  = (float*)(w + OFF_SCSH2);
    float* partS  = (float*)(w + OFF_PS);
    float* partSA = (float*)(w + OFF_PSA);
    float* partP  = (float*)(w + OFF_PP);
    float* partPA = (float*)(w + OFF_PPA);
    float* part2  = (float*)(w + OFF_P2);
    float* part2A = (float*)(w + OFF_P2A);
    float* feats  = (float*)(w + OFF_FE);
    float* featsp = (float*)(w + OFF_FP);
    int*   cnt    = (int*)(w + OFF_CNT);
    float* sbfp   = (float*)(w + OFF_SBP);
    float* sbf    = (float*)(w + OFF_SBF);
    unsigned short* bfq = (unsigned short*)(w + OFF_BFQ);

    const bool useq = (ws_size >= NEED_BFQ);

    if (useq) k_cvt<<<NBOND * 64 / (256 * 8), 256, 0, stream>>>(bondf, bfq);
    k_zero<<<(NN + 255) / 256, 256, 0, stream>>>(cnt);
    k_cnt<<<(NBOND + 255) / 256, 256, 0, stream>>>(bidx, cnt);
    if (useq) k_sbf<true><<<256, 256, 0, stream>>>(bondf, bfq, sbfp);
    else      k_sbf<false><<<256, 256, 0, stream>>>(bondf, bfq, sbfp);
    k_sbf2<<<1, 64, 0, stream>>>(sbfp, sbf);
    k_fc1<<<2500, 256, 0, stream>>>(site, fc1w, fc1b, h);

    for (int l = 0; l < LL; ++l) {
        const float* cw = convw + (size_t)l * 192 * 128;
        const float* cb = convb + l * 128;
        const float* wbp = cw + 128 * 128;
        k_proj<<<G_PROJ, 256, 0, stream>>>(h, cw, cb, cnt, hi, hj, partP);
        k_redw<<<125, 256, 0, stream>>>(partP, partPA, G_PROJ, 10);
        if (useq)
            k_stat<true><<<G_STAT, 256, 0, stream>>>(bondf, bfq, wbp, hi, hj, bidx, partS);
        else
            k_stat<false><<<G_STAT, 256, 0, stream>>>(bondf, bfq, wbp, hi, hj, bidx, partS);
        k_redw<<<128, 128, 0, stream>>>(partS, partSA, G_STAT, 8);
        k_fin1<<<1, 128, 0, stream>>>(partSA, partPA, sbf, wbp,
                                      bn1g + l * 128, bn1b + l * 128, scsh1);
        if (useq)
            k_fuse<true><<<G_FUSE, 192, 0, stream>>>(bondf, bfq, wbp, hi, hj, bidx,
                                                     scsh1, sbuf, part2);
        else
            k_fuse<false><<<G_FUSE, 192, 0, stream>>>(bondf, bfq, wbp, hi, hj, bidx,
                                                      scsh1, sbuf, part2);
        k_redw<<<128, 128, 0, stream>>>(part2, part2A, G_FUSE, 8);
        k_fin2<<<1, 128, 0, stream>>>(part2A, bn2g + l * 64, bn2b + l * 64, scsh2);
        k_upd<<<2500, 256, 0, stream>>>(h, sbuf, scsh2);
    }
    k_pool<<<128, 256, 0, stream>>>(h, cidx, feats);
    k_head1<<<1, 128, 0, stream>>>(feats, fap, topg, topb, featsp);
    k_head2<<<128, 128, 0, stream>>>(featsp, fc2w, fc2b, fc3w, fc3b, out);
}

// Round 7
// 633.008 us; speedup vs baseline: 1.2898x; 1.2898x over previous
//
#include <hip/hip_runtime.h>
#include <hip/hip_bf16.h>

// CGCNN forward. r3 structure (materialize gated-input tbuf) + swapped-operand MFMA:
//   t[n,m,:] = hi[n,:] + hj[idx[n,m],:] + bond[n,m,:]@w_b   (bias folded into hi)
// k_bond: mfma(wb_frag, bond_frag, acc) -> lane owns ONE bond, 4 consecutive cols/reg.
//   No t_lds staging: ushort4 hi/hj gathers, in-register stats, direct tbuf stores.
//   LDS 29.7KB (wbT resident 18.4 + A 9.2 + red 2). No __launch_bounds__ min-waves
//   (r4 lesson: VGPR clamp -> scratch spill). No analytic-mean prologue (r6 lesson:
//   k_sbf cost 114us > everything it saved).
// Transcendentals via HW exp2/log/rcp.

#define NN 40000
#define MM 12
#define AA 64
#define LL 3
#define CC 128
#define F0C 92
#define NBOND (NN*MM)
#define EPSBN 1e-5f

#define G_BOND 1250     // 7500 tiles of 64 bonds -> 6 tiles/block
#define NTILE 7500
#define G_APPLY 1250    // 1250 groups of 32 sites -> 1 iter/block
#define RED_B 125

#define L2E 1.4426950408889634f
#define LN2 0.6931471805599453f

typedef __attribute__((ext_vector_type(8))) short bf16x8;
typedef __attribute__((ext_vector_type(4))) float f32x4;

__device__ __forceinline__ float softplusf_(float x) {
    float e = __builtin_amdgcn_exp2f(-fabsf(x) * L2E);
    return fmaxf(x, 0.f) + __builtin_amdgcn_logf(1.f + e) * LN2;
}
__device__ __forceinline__ float sigmoidf_(float x) {
    return __builtin_amdgcn_rcpf(1.f + __builtin_amdgcn_exp2f(-x * L2E));
}
__device__ __forceinline__ unsigned short f2bf(float f) {
    unsigned int u = __float_as_uint(f);
    unsigned int r = (u + 0x7fffu + ((u >> 16) & 1u)) >> 16;
    return (unsigned short)r;
}
__device__ __forceinline__ float bf2f(unsigned short s) {
    return __uint_as_float(((unsigned int)s) << 16);
}

// ---------------- bond features f32 -> bf16, once ----------------
__global__ __launch_bounds__(256) void k_cvt(const float* __restrict__ in,
        unsigned short* __restrict__ out) {
    size_t i = ((size_t)blockIdx.x * 256 + threadIdx.x) * 8;
    float4 a = *(const float4*)&in[i];
    float4 b = *(const float4*)&in[i + 4];
    ushort4 ua, ub;
    ua.x = f2bf(a.x); ua.y = f2bf(a.y); ua.z = f2bf(a.z); ua.w = f2bf(a.w);
    ub.x = f2bf(b.x); ub.y = f2bf(b.y); ub.z = f2bf(b.z); ub.w = f2bf(b.w);
    *(ushort4*)&out[i] = ua;
    *(ushort4*)&out[i + 4] = ub;
}

// ---------------- fc1 ----------------
__global__ __launch_bounds__(256) void k_fc1(const float* __restrict__ site,
        const float* __restrict__ w, const float* __restrict__ b,
        float* __restrict__ h) {
    __shared__ float w_s[F0C][AA];
    __shared__ float x_s[16][F0C];
    int tid = threadIdx.x;
    for (int i = tid; i < F0C * AA; i += 256) w_s[i / AA][i % AA] = w[i];
    int n0 = blockIdx.x * 16;
    for (int i = tid; i < 16 * F0C; i += 256) x_s[i / F0C][i % F0C] = site[(size_t)n0 * F0C + i];
    __syncthreads();
    int d = tid & 63, ng = tid >> 6;
    float bb = b[d];
    float acc[4] = {bb, bb, bb, bb};
    #pragma unroll 4
    for (int k = 0; k < F0C; ++k) {
        float wv = w_s[k][d];
        acc[0] += x_s[ng][k] * wv;
        acc[1] += x_s[ng + 4][k] * wv;
        acc[2] += x_s[ng + 8][k] * wv;
        acc[3] += x_s[ng + 12][k] * wv;
    }
    #pragma unroll
    for (int rr = 0; rr < 4; ++rr)
        h[(size_t)(n0 + ng + rr * 4) * AA + d] = acc[rr];
}

// ---------------- proj: hi = h@w_i + bias, hj = h@w_j -> bf16 ----------------
__global__ __launch_bounds__(256) void k_proj(const float* __restrict__ h,
        const float* __restrict__ convw, const float* __restrict__ convb,
        unsigned short* __restrict__ hi, unsigned short* __restrict__ hj) {
    __shared__ float w_s[64][256];
    __shared__ float hT[64][36];
    int tid = threadIdx.x;
    for (int i = tid; i < 64 * 256; i += 256) {
        int k = i >> 8, c = i & 255;
        w_s[k][c] = convw[(size_t)((c < 128 ? k : 64 + k)) * 128 + (c & 127)];
    }
    int row0 = blockIdx.x * 32;
    for (int i = tid; i < 2048; i += 256) {
        int r = i >> 6, k = i & 63;
        hT[k][r] = h[(size_t)(row0 + r) * 64 + k];
    }
    __syncthreads();
    int c0 = (tid & 63) * 4;
    int r0 = (tid >> 6) * 8;
    float acc[8][4];
    #pragma unroll
    for (int r = 0; r < 8; ++r)
        #pragma unroll
        for (int i = 0; i < 4; ++i) acc[r][i] = 0.f;
    #pragma unroll 4
    for (int k = 0; k < 64; ++k) {
        float4 w4 = *(const float4*)&w_s[k][c0];
        float4 ha = *(const float4*)&hT[k][r0];
        float4 hb = *(const float4*)&hT[k][r0 + 4];
        float wv[4] = {w4.x, w4.y, w4.z, w4.w};
        float hv[8] = {ha.x, ha.y, ha.z, ha.w, hb.x, hb.y, hb.z, hb.w};
        #pragma unroll
        for (int r = 0; r < 8; ++r)
            #pragma unroll
            for (int i = 0; i < 4; ++i) acc[r][i] += hv[r] * wv[i];
    }
    bool isHi = (c0 < 128);
    int cc = isHi ? c0 : c0 - 128;
    float4 cb4 = make_float4(0.f, 0.f, 0.f, 0.f);
    if (isHi) cb4 = *(const float4*)&convb[c0];
    unsigned short* dst = isHi ? hi : hj;
    #pragma unroll
    for (int r = 0; r < 8; ++r) {
        int n = row0 + r0 + r;
        ushort4 o;
        o.x = f2bf(acc[r][0] + cb4.x);
        o.y = f2bf(acc[r][1] + cb4.y);
        o.z = f2bf(acc[r][2] + cb4.z);
        o.w = f2bf(acc[r][3] + cb4.w);
        *(ushort4*)&dst[(size_t)n * 128 + cc] = o;
    }
}

// ---------------- bond GEMM (swapped-operand MFMA) + t assembly + bn1 stats + tbuf ----------------
template<bool BFQ>
__global__ __launch_bounds__(256) void k_bond(const float* __restrict__ bf,
        const unsigned short* __restrict__ bfq,
        const float* __restrict__ wb,
        const unsigned short* __restrict__ hi, const unsigned short* __restrict__ hj,
        const int* __restrict__ bidx,
        unsigned short* __restrict__ tbuf,
        float* __restrict__ part1) {
    __shared__ unsigned short wbT[128][72];   // resident [col][k] bf16
    __shared__ unsigned short A_lds[64][72];  // [bond][k] bf16
    __shared__ float red[4][128];

    int tid = threadIdx.x;
    int lane = tid & 63, w = tid >> 6;
    int l15 = lane & 15, l4 = lane >> 4;

    for (int i = tid; i < 64 * 128; i += 256) {
        int k = i >> 7, c = i & 127;
        wbT[c][k] = f2bf(wb[i]);
    }

    float suml[8][4], sql[8][4];
    #pragma unroll
    for (int ct = 0; ct < 8; ++ct)
        #pragma unroll
        for (int r = 0; r < 4; ++r) { suml[ct][r] = 0.f; sql[ct][r] = 0.f; }

    int myb = w * 16 + l15;   // this thread's bond within the 64-bond tile
    for (int tile = blockIdx.x; tile < NTILE; tile += G_BOND) {
        int bond0 = tile * 64;
        __syncthreads();  // prev-tile MFMA reads of A_lds done (and wbT ready, iter 0)
        #pragma unroll
        for (int ii = 0; ii < 2; ++ii) {
            int idx = tid + ii * 256;
            int r = idx >> 3, k8 = (idx & 7) * 8;
            if constexpr (BFQ) {
                bf16x8 v = *(const bf16x8*)&bfq[((size_t)(bond0 + r)) * 64 + k8];
                *(bf16x8*)&A_lds[r][k8] = v;
            } else {
                float4 v0 = *(const float4*)&bf[((size_t)(bond0 + r)) * 64 + k8];
                float4 v1 = *(const float4*)&bf[((size_t)(bond0 + r)) * 64 + k8 + 4];
                ushort4 ua, ub;
                ua.x = f2bf(v0.x); ua.y = f2bf(v0.y); ua.z = f2bf(v0.z); ua.w = f2bf(v0.w);
                ub.x = f2bf(v1.x); ub.y = f2bf(v1.y); ub.z = f2bf(v1.z); ub.w = f2bf(v1.w);
                *(ushort4*)&A_lds[r][k8] = ua;
                *(ushort4*)&A_lds[r][k8 + 4] = ub;
            }
        }
        __syncthreads();

        f32x4 acc[8];
        #pragma unroll
        for (int ct = 0; ct < 8; ++ct) acc[ct] = (f32x4){0.f, 0.f, 0.f, 0.f};
        #pragma unroll
        for (int kh = 0; kh < 2; ++kh) {
            bf16x8 a = *(const bf16x8*)&A_lds[myb][kh * 32 + l4 * 8];
            #pragma unroll
            for (int ct = 0; ct < 8; ++ct) {
                bf16x8 wf = *(const bf16x8*)&wbT[ct * 16 + l15][kh * 32 + l4 * 8];
                acc[ct] = __builtin_amdgcn_mfma_f32_16x16x32_bf16(wf, a, acc[ct], 0, 0, 0);
            }
        }

        int bond = bond0 + myb;
        int n = bond / MM;
        int j = bidx[bond];
        const unsigned short* hin = hi + (size_t)n * 128;
        const unsigned short* hjn = hj + (size_t)j * 128;
        #pragma unroll
        for (int ct = 0; ct < 8; ++ct) {
            int c0 = ct * 16 + l4 * 4;
            ushort4 h4 = *(const ushort4*)&hin[c0];
            ushort4 j4 = *(const ushort4*)&hjn[c0];
            float hh[4] = {bf2f(h4.x), bf2f(h4.y), bf2f(h4.z), bf2f(h4.w)};
            float jj[4] = {bf2f(j4.x), bf2f(j4.y), bf2f(j4.z), bf2f(j4.w)};
            ushort4 o;
            unsigned short ov[4];
            #pragma unroll
            for (int r = 0; r < 4; ++r) {
                float t = acc[ct][r] + hh[r] + jj[r];
                suml[ct][r] += t;
                sql[ct][r] += t * t;
                ov[r] = f2bf(t);
            }
            o.x = ov[0]; o.y = ov[1]; o.z = ov[2]; o.w = ov[3];
            *(ushort4*)&tbuf[(size_t)bond * 128 + c0] = o;
        }
    }

    // stats reduce over the 16 l15-lanes (bonds), then across waves via LDS
    #pragma unroll
    for (int ct = 0; ct < 8; ++ct)
        #pragma unroll
        for (int r = 0; r < 4; ++r) {
            float s = suml[ct][r], q = sql[ct][r];
            s += __shfl_xor(s, 1); s += __shfl_xor(s, 2);
            s += __shfl_xor(s, 4); s += __shfl_xor(s, 8);
            q += __shfl_xor(q, 1); q += __shfl_xor(q, 2);
            q += __shfl_xor(q, 4); q += __shfl_xor(q, 8);
            suml[ct][r] = s; sql[ct][r] = q;
        }
    __syncthreads();
    if (l15 == 0) {
        #pragma unroll
        for (int ct = 0; ct < 8; ++ct)
            #pragma unroll
            for (int r = 0; r < 4; ++r)
                red[w][ct * 16 + l4 * 4 + r] = suml[ct][r];
    }
    __syncthreads();
    if (tid < 128)
        part1[(size_t)blockIdx.x * 256 + tid] =
            red[0][tid] + red[1][tid] + red[2][tid] + red[3][tid];
    __syncthreads();
    if (l15 == 0) {
        #pragma unroll
        for (int ct = 0; ct < 8; ++ct)
            #pragma unroll
            for (int r = 0; r < 4; ++r)
                red[w][ct * 16 + l4 * 4 + r] = sql[ct][r];
    }
    __syncthreads();
    if (tid < 128)
        part1[(size_t)blockIdx.x * 256 + 128 + tid] =
            red[0][tid] + red[1][tid] + red[2][tid] + red[3][tid];
}

// ---------------- stage-A reductions ----------------
__global__ __launch_bounds__(256) void k_red1(const float* __restrict__ in, float* __restrict__ out) {
    int tid = threadIdx.x, b = blockIdx.x;
    float acc = 0.f;
    for (int r = b * 10; r < b * 10 + 10; ++r) acc += in[(size_t)r * 256 + tid];
    out[(size_t)b * 256 + tid] = acc;
}
__global__ __launch_bounds__(128) void k_red2(const float* __restrict__ in, float* __restrict__ out) {
    int tid = threadIdx.x, b = blockIdx.x;
    float acc = 0.f;
    for (int r = b * 10; r < b * 10 + 10; ++r) acc += in[(size_t)r * 128 + tid];
    out[(size_t)b * 128 + tid] = acc;
}

// ---------------- finalize bn1 ----------------
__global__ __launch_bounds__(256) void k_fin1(const float* __restrict__ partA, const float* __restrict__ g,
                       const float* __restrict__ b, float* __restrict__ scsh) {
    __shared__ float sm[256];
    int tid = threadIdx.x;
    float acc = 0.f;
    for (int r = 0; r < RED_B; ++r) acc += partA[(size_t)r * 256 + tid];
    sm[tid] = acc;
    __syncthreads();
    if (tid < 128) {
        float m = sm[tid] / (float)NBOND;
        float v = sm[128 + tid] / (float)NBOND - m * m;
        float sc = g[tid] * rsqrtf(v + EPSBN);
        scsh[tid] = sc;
        scsh[128 + tid] = b[tid] - m * sc;
    }
}

// ---------------- finalize bn2 ----------------
__global__ __launch_bounds__(128) void k_fin2(const float* __restrict__ partB, const float* __restrict__ g,
                       const float* __restrict__ b, float* __restrict__ scsh2) {
    __shared__ float sm[128];
    int tid = threadIdx.x;
    float acc = 0.f;
    for (int r = 0; r < RED_B; ++r) acc += partB[(size_t)r * 128 + tid];
    sm[tid] = acc;
    __syncthreads();
    if (tid < 64) {
        float m = sm[tid] / (float)NN;
        float v = sm[64 + tid] / (float)NN - m * m;
        float sc = g[tid] * rsqrtf(v + EPSBN);
        scsh2[tid] = sc;
        scsh2[64 + tid] = b[tid] - m * sc;
    }
}

// ---------------- apply bn1 + gated sum over m + bn2 partial stats ----------------
__global__ __launch_bounds__(256) void k_apply(const unsigned short* __restrict__ tbuf,
        const float* __restrict__ scsh, float* __restrict__ s_out,
        float* __restrict__ part2) {
    __shared__ float red[32][64];
    int tid = threadIdx.x;
    int c8 = (tid & 7) * 8, sg = tid >> 3;
    float scf[8], shf[8], scc[8], shc[8];
    #pragma unroll
    for (int j = 0; j < 8; ++j) {
        scf[j] = scsh[c8 + j];       shf[j] = scsh[128 + c8 + j];
        scc[j] = scsh[64 + c8 + j];  shc[j] = scsh[192 + c8 + j];
    }
    float sum[8], sq[8];
    #pragma unroll
    for (int j = 0; j < 8; ++j) { sum[j] = 0.f; sq[j] = 0.f; }
    for (int q = blockIdx.x; q < NN / 32; q += G_APPLY) {
        int n = q * 32 + sg;
        const unsigned short* tb = tbuf + (size_t)n * (MM * 128);
        float sacc[8];
        #pragma unroll
        for (int j = 0; j < 8; ++j) sacc[j] = 0.f;
        #pragma unroll
        for (int m = 0; m < MM; ++m) {
            bf16x8 f8 = *(const bf16x8*)&tb[m * 128 + c8];
            bf16x8 s8 = *(const bf16x8*)&tb[m * 128 + 64 + c8];
            #pragma unroll
            for (int j = 0; j < 8; ++j) {
                float ff = bf2f((unsigned short)f8[j]);
                float ss = bf2f((unsigned short)s8[j]);
                sacc[j] += sigmoidf_(scf[j] * ff + shf[j]) * softplusf_(scc[j] * ss + shc[j]);
            }
        }
        float4 oa = make_float4(sacc[0], sacc[1], sacc[2], sacc[3]);
        float4 ob = make_float4(sacc[4], sacc[5], sacc[6], sacc[7]);
        *(float4*)&s_out[(size_t)n * 64 + c8] = oa;
        *(float4*)&s_out[(size_t)n * 64 + c8 + 4] = ob;
        #pragma unroll
        for (int j = 0; j < 8; ++j) { sum[j] += sacc[j]; sq[j] += sacc[j] * sacc[j]; }
    }
    #pragma unroll
    for (int j = 0; j < 8; ++j) red[sg][c8 + j] = sum[j];
    __syncthreads();
    if (tid < 64) {
        float t = 0.f;
        #pragma unroll
        for (int g = 0; g < 32; ++g) t += red[g][tid];
        part2[(size_t)blockIdx.x * 128 + tid] = t;
    }
    __syncthreads();
    #pragma unroll
    for (int j = 0; j < 8; ++j) red[sg][c8 + j] = sq[j];
    __syncthreads();
    if (tid < 64) {
        float t = 0.f;
        #pragma unroll
        for (int g = 0; g < 32; ++g) t += red[g][tid];
        part2[(size_t)blockIdx.x * 128 + 64 + tid] = t;
    }
}

// ---------------- h = softplus(h + bn2(s)) ----------------
__global__ __launch_bounds__(256) void k_upd(float* __restrict__ h, const float* __restrict__ s,
        const float* __restrict__ scsh2) {
    size_t i = ((size_t)blockIdx.x * 256 + threadIdx.x) * 4;
    int c0 = (int)(i & 63);
    float4 hv = *(const float4*)&h[i];
    float4 sv = *(const float4*)&s[i];
    float4 o;
    o.x = softplusf_(hv.x + scsh2[c0 + 0] * sv.x + scsh2[64 + c0 + 0]);
    o.y = softplusf_(hv.y + scsh2[c0 + 1] * sv.y + scsh2[64 + c0 + 1]);
    o.z = softplusf_(hv.z + scsh2[c0 + 2] * sv.z + scsh2[64 + c0 + 2]);
    o.w = softplusf_(hv.w + scsh2[c0 + 3] * sv.w + scsh2[64 + c0 + 3]);
    *(float4*)&h[i] = o;
}

// ---------------- pooling ----------------
__device__ __forceinline__ int lbound(const int* a, int n, int v) {
    int lo = 0, hi = n;
    while (lo < hi) { int mid = (lo + hi) >> 1; if (a[mid] < v) lo = mid + 1; else hi = mid; }
    return lo;
}

__global__ __launch_bounds__(256) void k_pool(const float* __restrict__ h,
        const int* __restrict__ cidx, float* __restrict__ feats) {
    __shared__ float red[4][68];
    __shared__ int bounds[2];
    int c = blockIdx.x, tid = threadIdx.x;
    if (tid == 0) {
        bounds[0] = lbound(cidx, NN, c);
        bounds[1] = lbound(cidx, NN, c + 1);
    }
    __syncthreads();
    int lo = bounds[0], hi = bounds[1];
    int d = tid & 63, g = tid >> 6;
    float acc = 0;
    for (int n = lo + g; n < hi; n += 4) acc += h[(size_t)n * 64 + d];
    red[g][d] = acc;
    __syncthreads();
    if (tid < 64) {
        float t = red[0][tid] + red[1][tid] + red[2][tid] + red[3][tid];
        int cnt = hi - lo;
        feats[(size_t)c * 65 + tid] = t / (float)(cnt > 0 ? cnt : 1);
    }
}

// ---------------- head ----------------
__global__ __launch_bounds__(128) void k_head1(float* __restrict__ feats, const float* __restrict__ fap,
        const float* __restrict__ g, const float* __restrict__ b, float* __restrict__ featsp) {
    int tid = threadIdx.x;
    if (tid < CC) feats[(size_t)tid * 65 + 64] = fap[tid];
    __syncthreads();
    if (tid < 65) {
        float s = 0;
        for (int r = 0; r < CC; ++r) s += feats[r * 65 + tid];
        float m = s / (float)CC;
        float v = 0;
        for (int r = 0; r < CC; ++r) { float d = feats[r * 65 + tid] - m; v += d * d; }
        v /= (float)CC;
        float sc = g[tid] * rsqrtf(v + EPSBN);
        float sh = b[tid] - m * sc;
        for (int r = 0; r < CC; ++r)
            featsp[r * 65 + tid] = softplusf_(sc * feats[r * 65 + tid] + sh);
    }
}

__global__ __launch_bounds__(128) void k_head2(const float* __restrict__ featsp,
        const float* __restrict__ fc2w, const float* __restrict__ fc2b,
        const float* __restrict__ fc3w, const float* __restrict__ fc3b,
        float* __restrict__ out) {
    __shared__ float fr[65];
    __shared__ float red[128];
    int r = blockIdx.x, tid = threadIdx.x;
    if (tid < 65) fr[tid] = featsp[(size_t)r * 65 + tid];
    __syncthreads();
    float acc = fc2b[tid];
    for (int k = 0; k < 65; ++k) acc += fr[k] * fc2w[k * 128 + tid];
    red[tid] = softplusf_(acc) * fc3w[tid];
    __syncthreads();
    for (int st = 64; st > 0; st >>= 1) {
        if (tid < st) red[tid] += red[tid + st];
        __syncthreads();
    }
    if (tid == 0) out[r] = red[0] + fc3b[0];
}

extern "C" void kernel_launch(void* const* d_in, const int* in_sizes, int n_in,
                              void* d_out, int out_size, void* d_ws, size_t ws_size,
                              hipStream_t stream) {
    const float* site  = (const float*)d_in[0];
    const float* bondf = (const float*)d_in[1];
    const float* fap   = (const float*)d_in[2];
    const float* fc1w  = (const float*)d_in[3];
    const float* fc1b  = (const float*)d_in[4];
    const float* convw = (const float*)d_in[5];
    const float* convb = (const float*)d_in[6];
    const float* bn1g  = (const float*)d_in[7];
    const float* bn1b  = (const float*)d_in[8];
    const float* bn2g  = (const float*)d_in[9];
    const float* bn2b  = (const float*)d_in[10];
    const float* topg  = (const float*)d_in[11];
    const float* topb  = (const float*)d_in[12];
    const float* fc2w  = (const float*)d_in[13];
    const float* fc2b  = (const float*)d_in[14];
    const float* fc3w  = (const float*)d_in[15];
    const float* fc3b  = (const float*)d_in[16];
    const int*   bidx  = (const int*)d_in[17];
    const int*   cidx  = (const int*)d_in[18];
    float* out = (float*)d_out;

    char* w = (char*)d_ws;
    constexpr size_t SZ_H  = (size_t)NN * 64 * 4;
    constexpr size_t SZ_HP = (size_t)NN * 128 * 2;   // hi/hj bf16
    constexpr size_t OFF_H  = 0;
    constexpr size_t OFF_HI = OFF_H + SZ_H;
    constexpr size_t OFF_HJ = OFF_HI + SZ_HP;
    constexpr size_t OFF_S  = OFF_HJ + SZ_HP;
    constexpr size_t OFF_SCSH1 = OFF_S + SZ_H;
    constexpr size_t OFF_SCSH2 = OFF_SCSH1 + 1024;
    constexpr size_t OFF_P1 = OFF_SCSH2 + 512;
    constexpr size_t OFF_P2 = OFF_P1 + (size_t)G_BOND * 256 * 4;
    constexpr size_t OFF_PA = OFF_P2 + (size_t)G_APPLY * 128 * 4;
    constexpr size_t OFF_PB = OFF_PA + (size_t)RED_B * 256 * 4;
    constexpr size_t OFF_FE = OFF_PB + (size_t)RED_B * 128 * 4;
    constexpr size_t OFF_FP = OFF_FE + 128 * 65 * 4;
    constexpr size_t OFF_T  = ((OFF_FP + 128 * 65 * 4) + 255) & ~(size_t)255;
    constexpr size_t OFF_BFQ = OFF_T + (size_t)NBOND * 128 * 2;
    constexpr size_t NEED_BFQ = OFF_BFQ + (size_t)NBOND * 64 * 2;

    float* h      = (float*)(w + OFF_H);
    unsigned short* hi = (unsigned short*)(w + OFF_HI);
    unsigned short* hj = (unsigned short*)(w + OFF_HJ);
    float* sbuf   = (float*)(w + OFF_S);
    float* scsh1  = (float*)(w + OFF_SCSH1);
    float* scsh2  = (float*)(w + OFF_SCSH2);
    float* part1  = (float*)(w + OFF_P1);
    float* part2  = (float*)(w + OFF_P2);
    float* partA  = (float*)(w + OFF_PA);
    float* partB  = (float*)(w + OFF_PB);
    float* feats  = (float*)(w + OFF_FE);
    float* featsp = (float*)(w + OFF_FP);
    unsigned short* tbuf = (unsigned short*)(w + OFF_T);
    unsigned short* bfq  = (unsigned short*)(w + OFF_BFQ);

    const bool useq = (ws_size >= NEED_BFQ);

    if (useq) k_cvt<<<NBOND * 64 / (256 * 8), 256, 0, stream>>>(bondf, bfq);
    k_fc1<<<2500, 256, 0, stream>>>(site, fc1w, fc1b, h);
    for (int l = 0; l < LL; ++l) {
        const float* cw = convw + (size_t)l * 192 * 128;
        const float* cb = convb + l * 128;
        k_proj<<<1250, 256, 0, stream>>>(h, cw, cb, hi, hj);
        if (useq)
            k_bond<true><<<G_BOND, 256, 0, stream>>>(bondf, bfq, cw + 128 * 128, hi, hj, bidx, tbuf, part1);
        else
            k_bond<false><<<G_BOND, 256, 0, stream>>>(bondf, bfq, cw + 128 * 128, hi, hj, bidx, tbuf, part1);
        k_red1<<<RED_B, 256, 0, stream>>>(part1, partA);
        k_fin1<<<1, 256, 0, stream>>>(partA, bn1g + l * 128, bn1b + l * 128, scsh1);
        k_apply<<<G_APPLY, 256, 0, stream>>>(tbuf, scsh1, sbuf, part2);
        k_red2<<<RED_B, 128, 0, stream>>>(part2, partB);
        k_fin2<<<1, 128, 0, stream>>>(partB, bn2g + l * 64, bn2b + l * 64, scsh2);
        k_upd<<<2500, 256, 0, stream>>>(h, sbuf, scsh2);
    }
    k_pool<<<128, 256, 0, stream>>>(h, cidx, feats);
    k_head1<<<1, 128, 0, stream>>>(feats, fap, topg, topb, featsp);
    k_head2<<<128, 128, 0, stream>>>(featsp, fc2w, fc2b, fc3w, fc3b, out);
}

// Round 8
// 540.732 us; speedup vs baseline: 1.5099x; 1.1706x over previous
//
#include <hip/hip_runtime.h>
#include <hip/hip_bf16.h>

// CGCNN forward. Materialize-tbuf structure + swapped-operand MFMA + staged writeout:
//   t[n,m,:] = hi[n,:] + hj[idx[n,m],:] + bond[n,m,:]@w_b   (bias folded into hi)
// k_bond per tile: stage A -> MFMA (lane owns one bond) -> raw acc to t_lds ->
//   coalesced writeout (16B t_lds reads + 16B hi/hj gathers + stats + 16B tbuf stores).
// r7 lesson: direct epilogue stores = 32B-granule scatter -> issue-bound (109us at 26% HBM).
// r4 lesson: no __launch_bounds__ min-waves clamp (spill). r6 lesson: no analytic-mean prologue.
// LDS: bfr in regs; t_lds[64][140] overlays dead wbT; A_lds[64][76] (pad 76 -> conflict-free
// MFMA reads); red overlays A_lds. 27.5KB total.

#define NN 40000
#define MM 12
#define AA 64
#define LL 3
#define CC 128
#define F0C 92
#define NBOND (NN*MM)
#define EPSBN 1e-5f

#define G_BOND 1250     // 7500 tiles of 64 bonds -> 6 tiles/block
#define NTILE 7500
#define G_APPLY 1250
#define RED_B 125

#define L2E 1.4426950408889634f
#define LN2 0.6931471805599453f

typedef __attribute__((ext_vector_type(8))) short bf16x8;
typedef __attribute__((ext_vector_type(4))) float f32x4;

__device__ __forceinline__ float softplusf_(float x) {
    float e = __builtin_amdgcn_exp2f(-fabsf(x) * L2E);
    return fmaxf(x, 0.f) + __builtin_amdgcn_logf(1.f + e) * LN2;
}
__device__ __forceinline__ float sigmoidf_(float x) {
    return __builtin_amdgcn_rcpf(1.f + __builtin_amdgcn_exp2f(-x * L2E));
}
__device__ __forceinline__ unsigned short f2bf(float f) {
    unsigned int u = __float_as_uint(f);
    unsigned int r = (u + 0x7fffu + ((u >> 16) & 1u)) >> 16;
    return (unsigned short)r;
}
__device__ __forceinline__ float bf2f(unsigned short s) {
    return __uint_as_float(((unsigned int)s) << 16);
}

// ---------------- bond features f32 -> bf16, once ----------------
__global__ __launch_bounds__(256) void k_cvt(const float* __restrict__ in,
        unsigned short* __restrict__ out) {
    size_t i = ((size_t)blockIdx.x * 256 + threadIdx.x) * 8;
    float4 a = *(const float4*)&in[i];
    float4 b = *(const float4*)&in[i + 4];
    ushort4 ua, ub;
    ua.x = f2bf(a.x); ua.y = f2bf(a.y); ua.z = f2bf(a.z); ua.w = f2bf(a.w);
    ub.x = f2bf(b.x); ub.y = f2bf(b.y); ub.z = f2bf(b.z); ub.w = f2bf(b.w);
    *(ushort4*)&out[i] = ua;
    *(ushort4*)&out[i + 4] = ub;
}

// ---------------- fc1 ----------------
__global__ __launch_bounds__(256) void k_fc1(const float* __restrict__ site,
        const float* __restrict__ w, const float* __restrict__ b,
        float* __restrict__ h) {
    __shared__ float w_s[F0C][AA];
    __shared__ float x_s[16][F0C];
    int tid = threadIdx.x;
    for (int i = tid; i < F0C * AA; i += 256) w_s[i / AA][i % AA] = w[i];
    int n0 = blockIdx.x * 16;
    for (int i = tid; i < 16 * F0C; i += 256) x_s[i / F0C][i % F0C] = site[(size_t)n0 * F0C + i];
    __syncthreads();
    int d = tid & 63, ng = tid >> 6;
    float bb = b[d];
    float acc[4] = {bb, bb, bb, bb};
    #pragma unroll 4
    for (int k = 0; k < F0C; ++k) {
        float wv = w_s[k][d];
        acc[0] += x_s[ng][k] * wv;
        acc[1] += x_s[ng + 4][k] * wv;
        acc[2] += x_s[ng + 8][k] * wv;
        acc[3] += x_s[ng + 12][k] * wv;
    }
    #pragma unroll
    for (int rr = 0; rr < 4; ++rr)
        h[(size_t)(n0 + ng + rr * 4) * AA + d] = acc[rr];
}

// ---------------- proj: hi = h@w_i + bias, hj = h@w_j -> bf16 ----------------
__global__ __launch_bounds__(256) void k_proj(const float* __restrict__ h,
        const float* __restrict__ convw, const float* __restrict__ convb,
        unsigned short* __restrict__ hi, unsigned short* __restrict__ hj) {
    __shared__ float w_s[64][256];
    __shared__ float hT[64][36];
    int tid = threadIdx.x;
    for (int i = tid; i < 64 * 256; i += 256) {
        int k = i >> 8, c = i & 255;
        w_s[k][c] = convw[(size_t)((c < 128 ? k : 64 + k)) * 128 + (c & 127)];
    }
    int row0 = blockIdx.x * 32;
    for (int i = tid; i < 2048; i += 256) {
        int r = i >> 6, k = i & 63;
        hT[k][r] = h[(size_t)(row0 + r) * 64 + k];
    }
    __syncthreads();
    int c0 = (tid & 63) * 4;
    int r0 = (tid >> 6) * 8;
    float acc[8][4];
    #pragma unroll
    for (int r = 0; r < 8; ++r)
        #pragma unroll
        for (int i = 0; i < 4; ++i) acc[r][i] = 0.f;
    #pragma unroll 4
    for (int k = 0; k < 64; ++k) {
        float4 w4 = *(const float4*)&w_s[k][c0];
        float4 ha = *(const float4*)&hT[k][r0];
        float4 hb = *(const float4*)&hT[k][r0 + 4];
        float wv[4] = {w4.x, w4.y, w4.z, w4.w};
        float hv[8] = {ha.x, ha.y, ha.z, ha.w, hb.x, hb.y, hb.z, hb.w};
        #pragma unroll
        for (int r = 0; r < 8; ++r)
            #pragma unroll
            for (int i = 0; i < 4; ++i) acc[r][i] += hv[r] * wv[i];
    }
    bool isHi = (c0 < 128);
    int cc = isHi ? c0 : c0 - 128;
    float4 cb4 = make_float4(0.f, 0.f, 0.f, 0.f);
    if (isHi) cb4 = *(const float4*)&convb[c0];
    unsigned short* dst = isHi ? hi : hj;
    #pragma unroll
    for (int r = 0; r < 8; ++r) {
        int n = row0 + r0 + r;
        ushort4 o;
        o.x = f2bf(acc[r][0] + cb4.x);
        o.y = f2bf(acc[r][1] + cb4.y);
        o.z = f2bf(acc[r][2] + cb4.z);
        o.w = f2bf(acc[r][3] + cb4.w);
        *(ushort4*)&dst[(size_t)n * 128 + cc] = o;
    }
}

// ---------------- bond GEMM + staged writeout + bn1 stats ----------------
template<bool BFQ>
__global__ __launch_bounds__(256) void k_bond(const float* __restrict__ bf,
        const unsigned short* __restrict__ bfq,
        const float* __restrict__ wb,
        const unsigned short* __restrict__ hi, const unsigned short* __restrict__ hj,
        const int* __restrict__ bidx,
        unsigned short* __restrict__ tbuf,
        float* __restrict__ part1) {
    __shared__ __align__(16) char buf0[128 * 72 * 2];  // wbT preload, then t_lds[64][140]
    __shared__ __align__(16) char buf1[64 * 76 * 2];   // A_lds[64][76], then red[16][128]
    auto wbT   = (unsigned short(*)[72])buf0;
    auto t_lds = (unsigned short(*)[140])buf0;
    auto A_lds = (unsigned short(*)[76])buf1;
    auto red   = (float(*)[128])buf1;

    int tid = threadIdx.x;
    int lane = tid & 63, w = tid >> 6;
    int l15 = lane & 15, l4 = lane >> 4;

    for (int i = tid; i < 64 * 128; i += 256) {
        int k = i >> 7, c = i & 127;
        wbT[c][k] = f2bf(wb[i]);
    }
    __syncthreads();
    bf16x8 bfr[2][8];   // wb fragments in registers; wbT dead after this
    #pragma unroll
    for (int kh = 0; kh < 2; ++kh)
        #pragma unroll
        for (int ct = 0; ct < 8; ++ct)
            bfr[kh][ct] = *(const bf16x8*)&wbT[ct * 16 + l15][kh * 32 + l4 * 8];

    int myb = w * 16 + l15;          // MFMA-phase bond
    int wr = tid >> 4, wc8 = (tid & 15) * 8;   // writeout-phase coords
    float suml[8], sql[8];
    #pragma unroll
    for (int k = 0; k < 8; ++k) { suml[k] = 0.f; sql[k] = 0.f; }

    for (int tile = blockIdx.x; tile < NTILE; tile += G_BOND) {
        int bond0 = tile * 64;
        __syncthreads();  // prev writeout (t_lds reads) + prev MFMA (A_lds reads) done
        #pragma unroll
        for (int ii = 0; ii < 2; ++ii) {
            int idx = tid + ii * 256;
            int r = idx >> 3, k8 = (idx & 7) * 8;
            if constexpr (BFQ) {
                bf16x8 v = *(const bf16x8*)&bfq[((size_t)(bond0 + r)) * 64 + k8];
                *(bf16x8*)&A_lds[r][k8] = v;
            } else {
                float4 v0 = *(const float4*)&bf[((size_t)(bond0 + r)) * 64 + k8];
                float4 v1 = *(const float4*)&bf[((size_t)(bond0 + r)) * 64 + k8 + 4];
                ushort4 ua, ub;
                ua.x = f2bf(v0.x); ua.y = f2bf(v0.y); ua.z = f2bf(v0.z); ua.w = f2bf(v0.w);
                ub.x = f2bf(v1.x); ub.y = f2bf(v1.y); ub.z = f2bf(v1.z); ub.w = f2bf(v1.w);
                *(ushort4*)&A_lds[r][k8] = ua;
                *(ushort4*)&A_lds[r][k8 + 4] = ub;
            }
        }
        __syncthreads();

        f32x4 acc[8];
        #pragma unroll
        for (int ct = 0; ct < 8; ++ct) acc[ct] = (f32x4){0.f, 0.f, 0.f, 0.f};
        #pragma unroll
        for (int kh = 0; kh < 2; ++kh) {
            bf16x8 a = *(const bf16x8*)&A_lds[myb][kh * 32 + l4 * 8];
            #pragma unroll
            for (int ct = 0; ct < 8; ++ct)
                acc[ct] = __builtin_amdgcn_mfma_f32_16x16x32_bf16(bfr[kh][ct], a, acc[ct], 0, 0, 0);
        }

        // stage raw GEMM result (bf16) into t_lds, per-bond layout
        #pragma unroll
        for (int ct = 0; ct < 8; ++ct) {
            ushort4 o;
            o.x = f2bf(acc[ct][0]); o.y = f2bf(acc[ct][1]);
            o.z = f2bf(acc[ct][2]); o.w = f2bf(acc[ct][3]);
            *(ushort4*)&t_lds[myb][ct * 16 + l4 * 4] = o;
        }
        __syncthreads();

        // writeout: 16 lanes cover a full 128-col row -> 256B runs everywhere
        #pragma unroll
        for (int rr = 0; rr < 4; ++rr) {
            int r = wr + rr * 16;
            int bond = bond0 + r;
            int n = bond / MM;
            int j = bidx[bond];
            bf16x8 g8  = *(const bf16x8*)&t_lds[r][wc8];
            bf16x8 hi8 = *(const bf16x8*)&hi[(size_t)n * 128 + wc8];
            bf16x8 hj8 = *(const bf16x8*)&hj[(size_t)j * 128 + wc8];
            bf16x8 o;
            #pragma unroll
            for (int k = 0; k < 8; ++k) {
                float t = bf2f((unsigned short)g8[k]) + bf2f((unsigned short)hi8[k])
                        + bf2f((unsigned short)hj8[k]);
                suml[k] += t;
                sql[k] += t * t;
                o[k] = (short)f2bf(t);
            }
            *(bf16x8*)&tbuf[(size_t)bond * 128 + wc8] = o;
        }
    }

    // stats: thread owns cols wc8..wc8+7 over its rows; reduce over 16 row-groups
    __syncthreads();   // A_lds dead -> red overlays
    #pragma unroll
    for (int k = 0; k < 8; ++k) red[wr][wc8 + k] = suml[k];
    __syncthreads();
    if (tid < 128) {
        float s = 0.f;
        #pragma unroll
        for (int g = 0; g < 16; ++g) s += red[g][tid];
        part1[(size_t)blockIdx.x * 256 + tid] = s;
    }
    __syncthreads();
    #pragma unroll
    for (int k = 0; k < 8; ++k) red[wr][wc8 + k] = sql[k];
    __syncthreads();
    if (tid < 128) {
        float s = 0.f;
        #pragma unroll
        for (int g = 0; g < 16; ++g) s += red[g][tid];
        part1[(size_t)blockIdx.x * 256 + 128 + tid] = s;
    }
}

// ---------------- stage-A reductions ----------------
__global__ __launch_bounds__(256) void k_red1(const float* __restrict__ in, float* __restrict__ out) {
    int tid = threadIdx.x, b = blockIdx.x;
    float acc = 0.f;
    for (int r = b * 10; r < b * 10 + 10; ++r) acc += in[(size_t)r * 256 + tid];
    out[(size_t)b * 256 + tid] = acc;
}
__global__ __launch_bounds__(128) void k_red2(const float* __restrict__ in, float* __restrict__ out) {
    int tid = threadIdx.x, b = blockIdx.x;
    float acc = 0.f;
    for (int r = b * 10; r < b * 10 + 10; ++r) acc += in[(size_t)r * 128 + tid];
    out[(size_t)b * 128 + tid] = acc;
}

// ---------------- finalize bn1 ----------------
__global__ __launch_bounds__(256) void k_fin1(const float* __restrict__ partA, const float* __restrict__ g,
                       const float* __restrict__ b, float* __restrict__ scsh) {
    __shared__ float sm[256];
    int tid = threadIdx.x;
    float acc = 0.f;
    for (int r = 0; r < RED_B; ++r) acc += partA[(size_t)r * 256 + tid];
    sm[tid] = acc;
    __syncthreads();
    if (tid < 128) {
        float m = sm[tid] / (float)NBOND;
        float v = sm[128 + tid] / (float)NBOND - m * m;
        float sc = g[tid] * rsqrtf(v + EPSBN);
        scsh[tid] = sc;
        scsh[128 + tid] = b[tid] - m * sc;
    }
}

// ---------------- finalize bn2 ----------------
__global__ __launch_bounds__(128) void k_fin2(const float* __restrict__ partB, const float* __restrict__ g,
                       const float* __restrict__ b, float* __restrict__ scsh2) {
    __shared__ float sm[128];
    int tid = threadIdx.x;
    float acc = 0.f;
    for (int r = 0; r < RED_B; ++r) acc += partB[(size_t)r * 128 + tid];
    sm[tid] = acc;
    __syncthreads();
    if (tid < 64) {
        float m = sm[tid] / (float)NN;
        float v = sm[64 + tid] / (float)NN - m * m;
        float sc = g[tid] * rsqrtf(v + EPSBN);
        scsh2[tid] = sc;
        scsh2[64 + tid] = b[tid] - m * sc;
    }
}

// ---------------- apply bn1 + gated sum over m + bn2 partial stats ----------------
__global__ __launch_bounds__(256) void k_apply(const unsigned short* __restrict__ tbuf,
        const float* __restrict__ scsh, float* __restrict__ s_out,
        float* __restrict__ part2) {
    __shared__ float red[32][64];
    int tid = threadIdx.x;
    int c8 = (tid & 7) * 8, sg = tid >> 3;
    float scf[8], shf[8], scc[8], shc[8];
    #pragma unroll
    for (int j = 0; j < 8; ++j) {
        scf[j] = scsh[c8 + j];       shf[j] = scsh[128 + c8 + j];
        scc[j] = scsh[64 + c8 + j];  shc[j] = scsh[192 + c8 + j];
    }
    float sum[8], sq[8];
    #pragma unroll
    for (int j = 0; j < 8; ++j) { sum[j] = 0.f; sq[j] = 0.f; }
    for (int q = blockIdx.x; q < NN / 32; q += G_APPLY) {
        int n = q * 32 + sg;
        const unsigned short* tb = tbuf + (size_t)n * (MM * 128);
        float sacc[8];
        #pragma unroll
        for (int j = 0; j < 8; ++j) sacc[j] = 0.f;
        #pragma unroll
        for (int m = 0; m < MM; ++m) {
            bf16x8 f8 = *(const bf16x8*)&tb[m * 128 + c8];
            bf16x8 s8 = *(const bf16x8*)&tb[m * 128 + 64 + c8];
            #pragma unroll
            for (int j = 0; j < 8; ++j) {
                float ff = bf2f((unsigned short)f8[j]);
                float ss = bf2f((unsigned short)s8[j]);
                sacc[j] += sigmoidf_(scf[j] * ff + shf[j]) * softplusf_(scc[j] * ss + shc[j]);
            }
        }
        float4 oa = make_float4(sacc[0], sacc[1], sacc[2], sacc[3]);
        float4 ob = make_float4(sacc[4], sacc[5], sacc[6], sacc[7]);
        *(float4*)&s_out[(size_t)n * 64 + c8] = oa;
        *(float4*)&s_out[(size_t)n * 64 + c8 + 4] = ob;
        #pragma unroll
        for (int j = 0; j < 8; ++j) { sum[j] += sacc[j]; sq[j] += sacc[j] * sacc[j]; }
    }
    #pragma unroll
    for (int j = 0; j < 8; ++j) red[sg][c8 + j] = sum[j];
    __syncthreads();
    if (tid < 64) {
        float t = 0.f;
        #pragma unroll
        for (int g = 0; g < 32; ++g) t += red[g][tid];
        part2[(size_t)blockIdx.x * 128 + tid] = t;
    }
    __syncthreads();
    #pragma unroll
    for (int j = 0; j < 8; ++j) red[sg][c8 + j] = sq[j];
    __syncthreads();
    if (tid < 64) {
        float t = 0.f;
        #pragma unroll
        for (int g = 0; g < 32; ++g) t += red[g][tid];
        part2[(size_t)blockIdx.x * 128 + 64 + tid] = t;
    }
}

// ---------------- h = softplus(h + bn2(s)) ----------------
__global__ __launch_bounds__(256) void k_upd(float* __restrict__ h, const float* __restrict__ s,
        const float* __restrict__ scsh2) {
    size_t i = ((size_t)blockIdx.x * 256 + threadIdx.x) * 4;
    int c0 = (int)(i & 63);
    float4 hv = *(const float4*)&h[i];
    float4 sv = *(const float4*)&s[i];
    float4 o;
    o.x = softplusf_(hv.x + scsh2[c0 + 0] * sv.x + scsh2[64 + c0 + 0]);
    o.y = softplusf_(hv.y + scsh2[c0 + 1] * sv.y + scsh2[64 + c0 + 1]);
    o.z = softplusf_(hv.z + scsh2[c0 + 2] * sv.z + scsh2[64 + c0 + 2]);
    o.w = softplusf_(hv.w + scsh2[c0 + 3] * sv.w + scsh2[64 + c0 + 3]);
    *(float4*)&h[i] = o;
}

// ---------------- pooling ----------------
__device__ __forceinline__ int lbound(const int* a, int n, int v) {
    int lo = 0, hi = n;
    while (lo < hi) { int mid = (lo + hi) >> 1; if (a[mid] < v) lo = mid + 1; else hi = mid; }
    return lo;
}

__global__ __launch_bounds__(256) void k_pool(const float* __restrict__ h,
        const int* __restrict__ cidx, float* __restrict__ feats) {
    __shared__ float red[4][68];
    __shared__ int bounds[2];
    int c = blockIdx.x, tid = threadIdx.x;
    if (tid == 0) {
        bounds[0] = lbound(cidx, NN, c);
        bounds[1] = lbound(cidx, NN, c + 1);
    }
    __syncthreads();
    int lo = bounds[0], hi = bounds[1];
    int d = tid & 63, g = tid >> 6;
    float acc = 0;
    for (int n = lo + g; n < hi; n += 4) acc += h[(size_t)n * 64 + d];
    red[g][d] = acc;
    __syncthreads();
    if (tid < 64) {
        float t = red[0][tid] + red[1][tid] + red[2][tid] + red[3][tid];
        int cnt = hi - lo;
        feats[(size_t)c * 65 + tid] = t / (float)(cnt > 0 ? cnt : 1);
    }
}

// ---------------- head ----------------
__global__ __launch_bounds__(128) void k_head1(float* __restrict__ feats, const float* __restrict__ fap,
        const float* __restrict__ g, const float* __restrict__ b, float* __restrict__ featsp) {
    int tid = threadIdx.x;
    if (tid < CC) feats[(size_t)tid * 65 + 64] = fap[tid];
    __syncthreads();
    if (tid < 65) {
        float s = 0;
        for (int r = 0; r < CC; ++r) s += feats[r * 65 + tid];
        float m = s / (float)CC;
        float v = 0;
        for (int r = 0; r < CC; ++r) { float d = feats[r * 65 + tid] - m; v += d * d; }
        v /= (float)CC;
        float sc = g[tid] * rsqrtf(v + EPSBN);
        float sh = b[tid] - m * sc;
        for (int r = 0; r < CC; ++r)
            featsp[r * 65 + tid] = softplusf_(sc * feats[r * 65 + tid] + sh);
    }
}

__global__ __launch_bounds__(128) void k_head2(const float* __restrict__ featsp,
        const float* __restrict__ fc2w, const float* __restrict__ fc2b,
        const float* __restrict__ fc3w, const float* __restrict__ fc3b,
        float* __restrict__ out) {
    __shared__ float fr[65];
    __shared__ float red[128];
    int r = blockIdx.x, tid = threadIdx.x;
    if (tid < 65) fr[tid] = featsp[(size_t)r * 65 + tid];
    __syncthreads();
    float acc = fc2b[tid];
    for (int k = 0; k < 65; ++k) acc += fr[k] * fc2w[k * 128 + tid];
    red[tid] = softplusf_(acc) * fc3w[tid];
    __syncthreads();
    for (int st = 64; st > 0; st >>= 1) {
        if (tid < st) red[tid] += red[tid + st];
        __syncthreads();
    }
    if (tid == 0) out[r] = red[0] + fc3b[0];
}

extern "C" void kernel_launch(void* const* d_in, const int* in_sizes, int n_in,
                              void* d_out, int out_size, void* d_ws, size_t ws_size,
                              hipStream_t stream) {
    const float* site  = (const float*)d_in[0];
    const float* bondf = (const float*)d_in[1];
    const float* fap   = (const float*)d_in[2];
    const float* fc1w  = (const float*)d_in[3];
    const float* fc1b  = (const float*)d_in[4];
    const float* convw = (const float*)d_in[5];
    const float* convb = (const float*)d_in[6];
    const float* bn1g  = (const float*)d_in[7];
    const float* bn1b  = (const float*)d_in[8];
    const float* bn2g  = (const float*)d_in[9];
    const float* bn2b  = (const float*)d_in[10];
    const float* topg  = (const float*)d_in[11];
    const float* topb  = (const float*)d_in[12];
    const float* fc2w  = (const float*)d_in[13];
    const float* fc2b  = (const float*)d_in[14];
    const float* fc3w  = (const float*)d_in[15];
    const float* fc3b  = (const float*)d_in[16];
    const int*   bidx  = (const int*)d_in[17];
    const int*   cidx  = (const int*)d_in[18];
    float* out = (float*)d_out;

    char* w = (char*)d_ws;
    constexpr size_t SZ_H  = (size_t)NN * 64 * 4;
    constexpr size_t SZ_HP = (size_t)NN * 128 * 2;   // hi/hj bf16
    constexpr size_t OFF_H  = 0;
    constexpr size_t OFF_HI = OFF_H + SZ_H;
    constexpr size_t OFF_HJ = OFF_HI + SZ_HP;
    constexpr size_t OFF_S  = OFF_HJ + SZ_HP;
    constexpr size_t OFF_SCSH1 = OFF_S + SZ_H;
    constexpr size_t OFF_SCSH2 = OFF_SCSH1 + 1024;
    constexpr size_t OFF_P1 = OFF_SCSH2 + 512;
    constexpr size_t OFF_P2 = OFF_P1 + (size_t)G_BOND * 256 * 4;
    constexpr size_t OFF_PA = OFF_P2 + (size_t)G_APPLY * 128 * 4;
    constexpr size_t OFF_PB = OFF_PA + (size_t)RED_B * 256 * 4;
    constexpr size_t OFF_FE = OFF_PB + (size_t)RED_B * 128 * 4;
    constexpr size_t OFF_FP = OFF_FE + 128 * 65 * 4;
    constexpr size_t OFF_T  = ((OFF_FP + 128 * 65 * 4) + 255) & ~(size_t)255;
    constexpr size_t OFF_BFQ = OFF_T + (size_t)NBOND * 128 * 2;
    constexpr size_t NEED_BFQ = OFF_BFQ + (size_t)NBOND * 64 * 2;

    float* h      = (float*)(w + OFF_H);
    unsigned short* hi = (unsigned short*)(w + OFF_HI);
    unsigned short* hj = (unsigned short*)(w + OFF_HJ);
    float* sbuf   = (float*)(w + OFF_S);
    float* scsh1  = (float*)(w + OFF_SCSH1);
    float* scsh2  = (float*)(w + OFF_SCSH2);
    float* part1  = (float*)(w + OFF_P1);
    float* part2  = (float*)(w + OFF_P2);
    float* partA  = (float*)(w + OFF_PA);
    float* partB  = (float*)(w + OFF_PB);
    float* feats  = (float*)(w + OFF_FE);
    float* featsp = (float*)(w + OFF_FP);
    unsigned short* tbuf = (unsigned short*)(w + OFF_T);
    unsigned short* bfq  = (unsigned short*)(w + OFF_BFQ);

    const bool useq = (ws_size >= NEED_BFQ);

    if (useq) k_cvt<<<NBOND * 64 / (256 * 8), 256, 0, stream>>>(bondf, bfq);
    k_fc1<<<2500, 256, 0, stream>>>(site, fc1w, fc1b, h);
    for (int l = 0; l < LL; ++l) {
        const float* cw = convw + (size_t)l * 192 * 128;
        const float* cb = convb + l * 128;
        k_proj<<<1250, 256, 0, stream>>>(h, cw, cb, hi, hj);
        if (useq)
            k_bond<true><<<G_BOND, 256, 0, stream>>>(bondf, bfq, cw + 128 * 128, hi, hj, bidx, tbuf, part1);
        else
            k_bond<false><<<G_BOND, 256, 0, stream>>>(bondf, bfq, cw + 128 * 128, hi, hj, bidx, tbuf, part1);
        k_red1<<<RED_B, 256, 0, stream>>>(part1, partA);
        k_fin1<<<1, 256, 0, stream>>>(partA, bn1g + l * 128, bn1b + l * 128, scsh1);
        k_apply<<<G_APPLY, 256, 0, stream>>>(tbuf, scsh1, sbuf, part2);
        k_red2<<<RED_B, 128, 0, stream>>>(part2, partB);
        k_fin2<<<1, 128, 0, stream>>>(partB, bn2g + l * 64, bn2b + l * 64, scsh2);
        k_upd<<<2500, 256, 0, stream>>>(h, sbuf, scsh2);
    }
    k_pool<<<128, 256, 0, stream>>>(h, cidx, feats);
    k_head1<<<1, 128, 0, stream>>>(feats, fap, topg, topb, featsp);
    k_head2<<<128, 128, 0, stream>>>(featsp, fc2w, fc2b, fc3w, fc3b, out);
}

// Round 9
// 520.212 us; speedup vs baseline: 1.5694x; 1.0394x over previous
//
#include <hip/hip_runtime.h>
#include <hip/hip_bf16.h>

// CGCNN forward. Materialize-tbuf + swapped-operand MFMA + staged writeout + pipelined k_bond:
//   t[n,m,:] = hi[n,:] + hj[idx[n,m],:] + bond[n,m,:]@w_b   (bias folded into hi)
// k_bond per tile (2 barriers, was 3):
//   issue next-tile global loads -> regs   (overlaps with everything below)
//   MFMA from A[cur] -> raw acc to t_lds -> sync
//   writeout (16B t_lds reads + 16B hi/hj gathers + stats + 16B tbuf stores)
//   ds_write staged regs -> A[cur^1] -> sync
// r7 lesson: direct epilogue stores scatter at 32B granule -> issue-bound.
// r4 lesson: no __launch_bounds__ min-waves clamp. r6 lesson: no analytic-mean prologue.
// LDS: t_lds[64][140] overlays dead wbT (18KB); A[2][64][76] dbuf (19KB); red overlays A. 37.9KB.

#define NN 40000
#define MM 12
#define AA 64
#define LL 3
#define CC 128
#define F0C 92
#define NBOND (NN*MM)
#define EPSBN 1e-5f

#define G_BOND 1250     // 7500 tiles of 64 bonds -> 6 tiles/block
#define NTILE 7500
#define G_APPLY 1250
#define RED_B 125

#define L2E 1.4426950408889634f
#define LN2 0.6931471805599453f

typedef __attribute__((ext_vector_type(8))) short bf16x8;
typedef __attribute__((ext_vector_type(4))) float f32x4;

__device__ __forceinline__ float softplusf_(float x) {
    float e = __builtin_amdgcn_exp2f(-fabsf(x) * L2E);
    return fmaxf(x, 0.f) + __builtin_amdgcn_logf(1.f + e) * LN2;
}
__device__ __forceinline__ float sigmoidf_(float x) {
    return __builtin_amdgcn_rcpf(1.f + __builtin_amdgcn_exp2f(-x * L2E));
}
__device__ __forceinline__ unsigned short f2bf(float f) {
    unsigned int u = __float_as_uint(f);
    unsigned int r = (u + 0x7fffu + ((u >> 16) & 1u)) >> 16;
    return (unsigned short)r;
}
__device__ __forceinline__ float bf2f(unsigned short s) {
    return __uint_as_float(((unsigned int)s) << 16);
}

// ---------------- bond features f32 -> bf16, once ----------------
__global__ __launch_bounds__(256) void k_cvt(const float* __restrict__ in,
        unsigned short* __restrict__ out) {
    size_t i = ((size_t)blockIdx.x * 256 + threadIdx.x) * 8;
    float4 a = *(const float4*)&in[i];
    float4 b = *(const float4*)&in[i + 4];
    ushort4 ua, ub;
    ua.x = f2bf(a.x); ua.y = f2bf(a.y); ua.z = f2bf(a.z); ua.w = f2bf(a.w);
    ub.x = f2bf(b.x); ub.y = f2bf(b.y); ub.z = f2bf(b.z); ub.w = f2bf(b.w);
    *(ushort4*)&out[i] = ua;
    *(ushort4*)&out[i + 4] = ub;
}

// ---------------- fc1 ----------------
__global__ __launch_bounds__(256) void k_fc1(const float* __restrict__ site,
        const float* __restrict__ w, const float* __restrict__ b,
        float* __restrict__ h) {
    __shared__ float w_s[F0C][AA];
    __shared__ float x_s[16][F0C];
    int tid = threadIdx.x;
    for (int i = tid; i < F0C * AA; i += 256) w_s[i / AA][i % AA] = w[i];
    int n0 = blockIdx.x * 16;
    for (int i = tid; i < 16 * F0C; i += 256) x_s[i / F0C][i % F0C] = site[(size_t)n0 * F0C + i];
    __syncthreads();
    int d = tid & 63, ng = tid >> 6;
    float bb = b[d];
    float acc[4] = {bb, bb, bb, bb};
    #pragma unroll 4
    for (int k = 0; k < F0C; ++k) {
        float wv = w_s[k][d];
        acc[0] += x_s[ng][k] * wv;
        acc[1] += x_s[ng + 4][k] * wv;
        acc[2] += x_s[ng + 8][k] * wv;
        acc[3] += x_s[ng + 12][k] * wv;
    }
    #pragma unroll
    for (int rr = 0; rr < 4; ++rr)
        h[(size_t)(n0 + ng + rr * 4) * AA + d] = acc[rr];
}

// ---------------- proj: hi = h@w_i + bias, hj = h@w_j -> bf16 ----------------
__global__ __launch_bounds__(256) void k_proj(const float* __restrict__ h,
        const float* __restrict__ convw, const float* __restrict__ convb,
        unsigned short* __restrict__ hi, unsigned short* __restrict__ hj) {
    __shared__ float w_s[64][256];
    __shared__ float hT[64][36];
    int tid = threadIdx.x;
    for (int i = tid; i < 64 * 256; i += 256) {
        int k = i >> 8, c = i & 255;
        w_s[k][c] = convw[(size_t)((c < 128 ? k : 64 + k)) * 128 + (c & 127)];
    }
    int row0 = blockIdx.x * 32;
    for (int i = tid; i < 2048; i += 256) {
        int r = i >> 6, k = i & 63;
        hT[k][r] = h[(size_t)(row0 + r) * 64 + k];
    }
    __syncthreads();
    int c0 = (tid & 63) * 4;
    int r0 = (tid >> 6) * 8;
    float acc[8][4];
    #pragma unroll
    for (int r = 0; r < 8; ++r)
        #pragma unroll
        for (int i = 0; i < 4; ++i) acc[r][i] = 0.f;
    #pragma unroll 4
    for (int k = 0; k < 64; ++k) {
        float4 w4 = *(const float4*)&w_s[k][c0];
        float4 ha = *(const float4*)&hT[k][r0];
        float4 hb = *(const float4*)&hT[k][r0 + 4];
        float wv[4] = {w4.x, w4.y, w4.z, w4.w};
        float hv[8] = {ha.x, ha.y, ha.z, ha.w, hb.x, hb.y, hb.z, hb.w};
        #pragma unroll
        for (int r = 0; r < 8; ++r)
            #pragma unroll
            for (int i = 0; i < 4; ++i) acc[r][i] += hv[r] * wv[i];
    }
    bool isHi = (c0 < 128);
    int cc = isHi ? c0 : c0 - 128;
    float4 cb4 = make_float4(0.f, 0.f, 0.f, 0.f);
    if (isHi) cb4 = *(const float4*)&convb[c0];
    unsigned short* dst = isHi ? hi : hj;
    #pragma unroll
    for (int r = 0; r < 8; ++r) {
        int n = row0 + r0 + r;
        ushort4 o;
        o.x = f2bf(acc[r][0] + cb4.x);
        o.y = f2bf(acc[r][1] + cb4.y);
        o.z = f2bf(acc[r][2] + cb4.z);
        o.w = f2bf(acc[r][3] + cb4.w);
        *(ushort4*)&dst[(size_t)n * 128 + cc] = o;
    }
}

// ---------------- bond GEMM, pipelined: reg-staged dbuf A + staged writeout + bn1 stats ----------------
template<bool BFQ>
__global__ __launch_bounds__(256) void k_bond(const float* __restrict__ bf,
        const unsigned short* __restrict__ bfq,
        const float* __restrict__ wb,
        const unsigned short* __restrict__ hi, const unsigned short* __restrict__ hj,
        const int* __restrict__ bidx,
        unsigned short* __restrict__ tbuf,
        float* __restrict__ part1) {
    __shared__ __align__(16) char buf0[128 * 72 * 2];      // wbT preload, then t_lds[64][140]
    __shared__ __align__(16) char bufA[2][64 * 76 * 2];    // double-buffered A; red overlays [0]
    auto wbT   = (unsigned short(*)[72])buf0;
    auto t_lds = (unsigned short(*)[140])buf0;
    auto red   = (float(*)[128])bufA[0];

    int tid = threadIdx.x;
    int lane = tid & 63, w = tid >> 6;
    int l15 = lane & 15, l4 = lane >> 4;

    for (int i = tid; i < 64 * 128; i += 256) {
        int k = i >> 7, c = i & 127;
        wbT[c][k] = f2bf(wb[i]);
    }
    __syncthreads();
    bf16x8 bfr[2][8];   // wb fragments in registers; wbT dead after (sync below covers reads)
    #pragma unroll
    for (int kh = 0; kh < 2; ++kh)
        #pragma unroll
        for (int ct = 0; ct < 8; ++ct)
            bfr[kh][ct] = *(const bf16x8*)&wbT[ct * 16 + l15][kh * 32 + l4 * 8];

    int myb = w * 16 + l15;                    // MFMA-phase bond
    int wr = tid >> 4, wc8 = (tid & 15) * 8;   // writeout-phase coords
    int sr = tid >> 3, sk8 = (tid & 7) * 8;    // staging coords (2 chunks/thread)
    float suml[8], sql[8];
    #pragma unroll
    for (int k = 0; k < 8; ++k) { suml[k] = 0.f; sql[k] = 0.f; }

    // prologue: stage tile0 through regs into A[0]
    {
        int bond0 = blockIdx.x * 64;
        auto A0 = (unsigned short(*)[76])bufA[0];
        if constexpr (BFQ) {
            bf16x8 s0 = *(const bf16x8*)&bfq[((size_t)(bond0 + sr)) * 64 + sk8];
            bf16x8 s1 = *(const bf16x8*)&bfq[((size_t)(bond0 + sr + 32)) * 64 + sk8];
            *(bf16x8*)&A0[sr][sk8] = s0;
            *(bf16x8*)&A0[sr + 32][sk8] = s1;
        } else {
            #pragma unroll
            for (int ii = 0; ii < 2; ++ii) {
                int r = sr + ii * 32;
                float4 v0 = *(const float4*)&bf[((size_t)(bond0 + r)) * 64 + sk8];
                float4 v1 = *(const float4*)&bf[((size_t)(bond0 + r)) * 64 + sk8 + 4];
                ushort4 ua, ub;
                ua.x = f2bf(v0.x); ua.y = f2bf(v0.y); ua.z = f2bf(v0.z); ua.w = f2bf(v0.w);
                ub.x = f2bf(v1.x); ub.y = f2bf(v1.y); ub.z = f2bf(v1.z); ub.w = f2bf(v1.w);
                *(ushort4*)&A0[r][sk8] = ua;
                *(ushort4*)&A0[r][sk8 + 4] = ub;
            }
        }
    }
    __syncthreads();   // A[0] ready; also fences bfr reads of wbT before t_lds overlays it

    int it = 0;
    for (int tile = blockIdx.x; tile < NTILE; tile += G_BOND, ++it) {
        int bond0 = tile * 64;
        auto Acur = (unsigned short(*)[76])bufA[it & 1];
        auto Anxt = (unsigned short(*)[76])bufA[(it & 1) ^ 1];
        bool has_next = (tile + G_BOND < NTILE);

        // 1. issue next-tile staging loads (no dependencies -> overlap everything below)
        bf16x8 st0, st1;
        float4 nf0[2], nf1[2];
        if (has_next) {
            int nb0 = (tile + G_BOND) * 64;
            if constexpr (BFQ) {
                st0 = *(const bf16x8*)&bfq[((size_t)(nb0 + sr)) * 64 + sk8];
                st1 = *(const bf16x8*)&bfq[((size_t)(nb0 + sr + 32)) * 64 + sk8];
            } else {
                #pragma unroll
                for (int ii = 0; ii < 2; ++ii) {
                    int r = sr + ii * 32;
                    nf0[ii] = *(const float4*)&bf[((size_t)(nb0 + r)) * 64 + sk8];
                    nf1[ii] = *(const float4*)&bf[((size_t)(nb0 + r)) * 64 + sk8 + 4];
                }
            }
        }

        // 2. MFMA current tile
        f32x4 acc[8];
        #pragma unroll
        for (int ct = 0; ct < 8; ++ct) acc[ct] = (f32x4){0.f, 0.f, 0.f, 0.f};
        #pragma unroll
        for (int kh = 0; kh < 2; ++kh) {
            bf16x8 a = *(const bf16x8*)&Acur[myb][kh * 32 + l4 * 8];
            #pragma unroll
            for (int ct = 0; ct < 8; ++ct)
                acc[ct] = __builtin_amdgcn_mfma_f32_16x16x32_bf16(bfr[kh][ct], a, acc[ct], 0, 0, 0);
        }

        // 3. stage raw acc (bf16) into t_lds, per-bond layout
        #pragma unroll
        for (int ct = 0; ct < 8; ++ct) {
            ushort4 o;
            o.x = f2bf(acc[ct][0]); o.y = f2bf(acc[ct][1]);
            o.z = f2bf(acc[ct][2]); o.w = f2bf(acc[ct][3]);
            *(ushort4*)&t_lds[myb][ct * 16 + l4 * 4] = o;
        }
        __syncthreads();   // t_lds ready; Acur fully consumed

        // 4. writeout: 16 lanes cover a full 128-col row -> 256B runs
        #pragma unroll
        for (int rr = 0; rr < 4; ++rr) {
            int r = wr + rr * 16;
            int bond = bond0 + r;
            int n = bond / MM;
            int j = bidx[bond];
            bf16x8 g8  = *(const bf16x8*)&t_lds[r][wc8];
            bf16x8 hi8 = *(const bf16x8*)&hi[(size_t)n * 128 + wc8];
            bf16x8 hj8 = *(const bf16x8*)&hj[(size_t)j * 128 + wc8];
            bf16x8 o;
            #pragma unroll
            for (int k = 0; k < 8; ++k) {
                float t = bf2f((unsigned short)g8[k]) + bf2f((unsigned short)hi8[k])
                        + bf2f((unsigned short)hj8[k]);
                suml[k] += t;
                sql[k] += t * t;
                o[k] = (short)f2bf(t);
            }
            *(bf16x8*)&tbuf[(size_t)bond * 128 + wc8] = o;
        }

        // 5. commit staged regs into A[next]
        if (has_next) {
            if constexpr (BFQ) {
                *(bf16x8*)&Anxt[sr][sk8] = st0;
                *(bf16x8*)&Anxt[sr + 32][sk8] = st1;
            } else {
                #pragma unroll
                for (int ii = 0; ii < 2; ++ii) {
                    int r = sr + ii * 32;
                    ushort4 ua, ub;
                    ua.x = f2bf(nf0[ii].x); ua.y = f2bf(nf0[ii].y);
                    ua.z = f2bf(nf0[ii].z); ua.w = f2bf(nf0[ii].w);
                    ub.x = f2bf(nf1[ii].x); ub.y = f2bf(nf1[ii].y);
                    ub.z = f2bf(nf1[ii].z); ub.w = f2bf(nf1[ii].w);
                    *(ushort4*)&Anxt[r][sk8] = ua;
                    *(ushort4*)&Anxt[r][sk8 + 4] = ub;
                }
            }
        }
        __syncthreads();   // A[next] ready; t_lds fully read before next overwrite
    }

    // stats: thread owns cols wc8..wc8+7; reduce over 16 row-groups (red overlays bufA[0])
    #pragma unroll
    for (int k = 0; k < 8; ++k) red[wr][wc8 + k] = suml[k];
    __syncthreads();
    if (tid < 128) {
        float s = 0.f;
        #pragma unroll
        for (int g = 0; g < 16; ++g) s += red[g][tid];
        part1[(size_t)blockIdx.x * 256 + tid] = s;
    }
    __syncthreads();
    #pragma unroll
    for (int k = 0; k < 8; ++k) red[wr][wc8 + k] = sql[k];
    __syncthreads();
    if (tid < 128) {
        float s = 0.f;
        #pragma unroll
        for (int g = 0; g < 16; ++g) s += red[g][tid];
        part1[(size_t)blockIdx.x * 256 + 128 + tid] = s;
    }
}

// ---------------- stage-A reductions ----------------
__global__ __launch_bounds__(256) void k_red1(const float* __restrict__ in, float* __restrict__ out) {
    int tid = threadIdx.x, b = blockIdx.x;
    float acc = 0.f;
    for (int r = b * 10; r < b * 10 + 10; ++r) acc += in[(size_t)r * 256 + tid];
    out[(size_t)b * 256 + tid] = acc;
}
__global__ __launch_bounds__(128) void k_red2(const float* __restrict__ in, float* __restrict__ out) {
    int tid = threadIdx.x, b = blockIdx.x;
    float acc = 0.f;
    for (int r = b * 10; r < b * 10 + 10; ++r) acc += in[(size_t)r * 128 + tid];
    out[(size_t)b * 128 + tid] = acc;
}

// ---------------- finalize bn1 ----------------
__global__ __launch_bounds__(256) void k_fin1(const float* __restrict__ partA, const float* __restrict__ g,
                       const float* __restrict__ b, float* __restrict__ scsh) {
    __shared__ float sm[256];
    int tid = threadIdx.x;
    float acc = 0.f;
    for (int r = 0; r < RED_B; ++r) acc += partA[(size_t)r * 256 + tid];
    sm[tid] = acc;
    __syncthreads();
    if (tid < 128) {
        float m = sm[tid] / (float)NBOND;
        float v = sm[128 + tid] / (float)NBOND - m * m;
        float sc = g[tid] * rsqrtf(v + EPSBN);
        scsh[tid] = sc;
        scsh[128 + tid] = b[tid] - m * sc;
    }
}

// ---------------- finalize bn2 ----------------
__global__ __launch_bounds__(128) void k_fin2(const float* __restrict__ partB, const float* __restrict__ g,
                       const float* __restrict__ b, float* __restrict__ scsh2) {
    __shared__ float sm[128];
    int tid = threadIdx.x;
    float acc = 0.f;
    for (int r = 0; r < RED_B; ++r) acc += partB[(size_t)r * 128 + tid];
    sm[tid] = acc;
    __syncthreads();
    if (tid < 64) {
        float m = sm[tid] / (float)NN;
        float v = sm[64 + tid] / (float)NN - m * m;
        float sc = g[tid] * rsqrtf(v + EPSBN);
        scsh2[tid] = sc;
        scsh2[64 + tid] = b[tid] - m * sc;
    }
}

// ---------------- apply bn1 + gated sum over m + bn2 partial stats ----------------
__global__ __launch_bounds__(256) void k_apply(const unsigned short* __restrict__ tbuf,
        const float* __restrict__ scsh, float* __restrict__ s_out,
        float* __restrict__ part2) {
    __shared__ float red[32][64];
    int tid = threadIdx.x;
    int c8 = (tid & 7) * 8, sg = tid >> 3;
    float scf[8], shf[8], scc[8], shc[8];
    #pragma unroll
    for (int j = 0; j < 8; ++j) {
        scf[j] = scsh[c8 + j];       shf[j] = scsh[128 + c8 + j];
        scc[j] = scsh[64 + c8 + j];  shc[j] = scsh[192 + c8 + j];
    }
    float sum[8], sq[8];
    #pragma unroll
    for (int j = 0; j < 8; ++j) { sum[j] = 0.f; sq[j] = 0.f; }
    for (int q = blockIdx.x; q < NN / 32; q += G_APPLY) {
        int n = q * 32 + sg;
        const unsigned short* tb = tbuf + (size_t)n * (MM * 128);
        float sacc[8];
        #pragma unroll
        for (int j = 0; j < 8; ++j) sacc[j] = 0.f;
        #pragma unroll
        for (int m = 0; m < MM; ++m) {
            bf16x8 f8 = *(const bf16x8*)&tb[m * 128 + c8];
            bf16x8 s8 = *(const bf16x8*)&tb[m * 128 + 64 + c8];
            #pragma unroll
            for (int j = 0; j < 8; ++j) {
                float ff = bf2f((unsigned short)f8[j]);
                float ss = bf2f((unsigned short)s8[j]);
                sacc[j] += sigmoidf_(scf[j] * ff + shf[j]) * softplusf_(scc[j] * ss + shc[j]);
            }
        }
        float4 oa = make_float4(sacc[0], sacc[1], sacc[2], sacc[3]);
        float4 ob = make_float4(sacc[4], sacc[5], sacc[6], sacc[7]);
        *(float4*)&s_out[(size_t)n * 64 + c8] = oa;
        *(float4*)&s_out[(size_t)n * 64 + c8 + 4] = ob;
        #pragma unroll
        for (int j = 0; j < 8; ++j) { sum[j] += sacc[j]; sq[j] += sacc[j] * sacc[j]; }
    }
    #pragma unroll
    for (int j = 0; j < 8; ++j) red[sg][c8 + j] = sum[j];
    __syncthreads();
    if (tid < 64) {
        float t = 0.f;
        #pragma unroll
        for (int g = 0; g < 32; ++g) t += red[g][tid];
        part2[(size_t)blockIdx.x * 128 + tid] = t;
    }
    __syncthreads();
    #pragma unroll
    for (int j = 0; j < 8; ++j) red[sg][c8 + j] = sq[j];
    __syncthreads();
    if (tid < 64) {
        float t = 0.f;
        #pragma unroll
        for (int g = 0; g < 32; ++g) t += red[g][tid];
        part2[(size_t)blockIdx.x * 128 + 64 + tid] = t;
    }
}

// ---------------- h = softplus(h + bn2(s)) ----------------
__global__ __launch_bounds__(256) void k_upd(float* __restrict__ h, const float* __restrict__ s,
        const float* __restrict__ scsh2) {
    size_t i = ((size_t)blockIdx.x * 256 + threadIdx.x) * 4;
    int c0 = (int)(i & 63);
    float4 hv = *(const float4*)&h[i];
    float4 sv = *(const float4*)&s[i];
    float4 o;
    o.x = softplusf_(hv.x + scsh2[c0 + 0] * sv.x + scsh2[64 + c0 + 0]);
    o.y = softplusf_(hv.y + scsh2[c0 + 1] * sv.y + scsh2[64 + c0 + 1]);
    o.z = softplusf_(hv.z + scsh2[c0 + 2] * sv.z + scsh2[64 + c0 + 2]);
    o.w = softplusf_(hv.w + scsh2[c0 + 3] * sv.w + scsh2[64 + c0 + 3]);
    *(float4*)&h[i] = o;
}

// ---------------- pooling ----------------
__device__ __forceinline__ int lbound(const int* a, int n, int v) {
    int lo = 0, hi = n;
    while (lo < hi) { int mid = (lo + hi) >> 1; if (a[mid] < v) lo = mid + 1; else hi = mid; }
    return lo;
}

__global__ __launch_bounds__(256) void k_pool(const float* __restrict__ h,
        const int* __restrict__ cidx, float* __restrict__ feats) {
    __shared__ float red[4][68];
    __shared__ int bounds[2];
    int c = blockIdx.x, tid = threadIdx.x;
    if (tid == 0) {
        bounds[0] = lbound(cidx, NN, c);
        bounds[1] = lbound(cidx, NN, c + 1);
    }
    __syncthreads();
    int lo = bounds[0], hi = bounds[1];
    int d = tid & 63, g = tid >> 6;
    float acc = 0;
    for (int n = lo + g; n < hi; n += 4) acc += h[(size_t)n * 64 + d];
    red[g][d] = acc;
    __syncthreads();
    if (tid < 64) {
        float t = red[0][tid] + red[1][tid] + red[2][tid] + red[3][tid];
        int cnt = hi - lo;
        feats[(size_t)c * 65 + tid] = t / (float)(cnt > 0 ? cnt : 1);
    }
}

// ---------------- head ----------------
__global__ __launch_bounds__(128) void k_head1(float* __restrict__ feats, const float* __restrict__ fap,
        const float* __restrict__ g, const float* __restrict__ b, float* __restrict__ featsp) {
    int tid = threadIdx.x;
    if (tid < CC) feats[(size_t)tid * 65 + 64] = fap[tid];
    __syncthreads();
    if (tid < 65) {
        float s = 0;
        for (int r = 0; r < CC; ++r) s += feats[r * 65 + tid];
        float m = s / (float)CC;
        float v = 0;
        for (int r = 0; r < CC; ++r) { float d = feats[r * 65 + tid] - m; v += d * d; }
        v /= (float)CC;
        float sc = g[tid] * rsqrtf(v + EPSBN);
        float sh = b[tid] - m * sc;
        for (int r = 0; r < CC; ++r)
            featsp[r * 65 + tid] = softplusf_(sc * feats[r * 65 + tid] + sh);
    }
}

__global__ __launch_bounds__(128) void k_head2(const float* __restrict__ featsp,
        const float* __restrict__ fc2w, const float* __restrict__ fc2b,
        const float* __restrict__ fc3w, const float* __restrict__ fc3b,
        float* __restrict__ out) {
    __shared__ float fr[65];
    __shared__ float red[128];
    int r = blockIdx.x, tid = threadIdx.x;
    if (tid < 65) fr[tid] = featsp[(size_t)r * 65 + tid];
    __syncthreads();
    float acc = fc2b[tid];
    for (int k = 0; k < 65; ++k) acc += fr[k] * fc2w[k * 128 + tid];
    red[tid] = softplusf_(acc) * fc3w[tid];
    __syncthreads();
    for (int st = 64; st > 0; st >>= 1) {
        if (tid < st) red[tid] += red[tid + st];
        __syncthreads();
    }
    if (tid == 0) out[r] = red[0] + fc3b[0];
}

extern "C" void kernel_launch(void* const* d_in, const int* in_sizes, int n_in,
                              void* d_out, int out_size, void* d_ws, size_t ws_size,
                              hipStream_t stream) {
    const float* site  = (const float*)d_in[0];
    const float* bondf = (const float*)d_in[1];
    const float* fap   = (const float*)d_in[2];
    const float* fc1w  = (const float*)d_in[3];
    const float* fc1b  = (const float*)d_in[4];
    const float* convw = (const float*)d_in[5];
    const float* convb = (const float*)d_in[6];
    const float* bn1g  = (const float*)d_in[7];
    const float* bn1b  = (const float*)d_in[8];
    const float* bn2g  = (const float*)d_in[9];
    const float* bn2b  = (const float*)d_in[10];
    const float* topg  = (const float*)d_in[11];
    const float* topb  = (const float*)d_in[12];
    const float* fc2w  = (const float*)d_in[13];
    const float* fc2b  = (const float*)d_in[14];
    const float* fc3w  = (const float*)d_in[15];
    const float* fc3b  = (const float*)d_in[16];
    const int*   bidx  = (const int*)d_in[17];
    const int*   cidx  = (const int*)d_in[18];
    float* out = (float*)d_out;

    char* w = (char*)d_ws;
    constexpr size_t SZ_H  = (size_t)NN * 64 * 4;
    constexpr size_t SZ_HP = (size_t)NN * 128 * 2;   // hi/hj bf16
    constexpr size_t OFF_H  = 0;
    constexpr size_t OFF_HI = OFF_H + SZ_H;
    constexpr size_t OFF_HJ = OFF_HI + SZ_HP;
    constexpr size_t OFF_S  = OFF_HJ + SZ_HP;
    constexpr size_t OFF_SCSH1 = OFF_S + SZ_H;
    constexpr size_t OFF_SCSH2 = OFF_SCSH1 + 1024;
    constexpr size_t OFF_P1 = OFF_SCSH2 + 512;
    constexpr size_t OFF_P2 = OFF_P1 + (size_t)G_BOND * 256 * 4;
    constexpr size_t OFF_PA = OFF_P2 + (size_t)G_APPLY * 128 * 4;
    constexpr size_t OFF_PB = OFF_PA + (size_t)RED_B * 256 * 4;
    constexpr size_t OFF_FE = OFF_PB + (size_t)RED_B * 128 * 4;
    constexpr size_t OFF_FP = OFF_FE + 128 * 65 * 4;
    constexpr size_t OFF_T  = ((OFF_FP + 128 * 65 * 4) + 255) & ~(size_t)255;
    constexpr size_t OFF_BFQ = OFF_T + (size_t)NBOND * 128 * 2;
    constexpr size_t NEED_BFQ = OFF_BFQ + (size_t)NBOND * 64 * 2;

    float* h      = (float*)(w + OFF_H);
    unsigned short* hi = (unsigned short*)(w + OFF_HI);
    unsigned short* hj = (unsigned short*)(w + OFF_HJ);
    float* sbuf   = (float*)(w + OFF_S);
    float* scsh1  = (float*)(w + OFF_SCSH1);
    float* scsh2  = (float*)(w + OFF_SCSH2);
    float* part1  = (float*)(w + OFF_P1);
    float* part2  = (float*)(w + OFF_P2);
    float* partA  = (float*)(w + OFF_PA);
    float* partB  = (float*)(w + OFF_PB);
    float* feats  = (float*)(w + OFF_FE);
    float* featsp = (float*)(w + OFF_FP);
    unsigned short* tbuf = (unsigned short*)(w + OFF_T);
    unsigned short* bfq  = (unsigned short*)(w + OFF_BFQ);

    const bool useq = (ws_size >= NEED_BFQ);

    if (useq) k_cvt<<<NBOND * 64 / (256 * 8), 256, 0, stream>>>(bondf, bfq);
    k_fc1<<<2500, 256, 0, stream>>>(site, fc1w, fc1b, h);
    for (int l = 0; l < LL; ++l) {
        const float* cw = convw + (size_t)l * 192 * 128;
        const float* cb = convb + l * 128;
        k_proj<<<1250, 256, 0, stream>>>(h, cw, cb, hi, hj);
        if (useq)
            k_bond<true><<<G_BOND, 256, 0, stream>>>(bondf, bfq, cw + 128 * 128, hi, hj, bidx, tbuf, part1);
        else
            k_bond<false><<<G_BOND, 256, 0, stream>>>(bondf, bfq, cw + 128 * 128, hi, hj, bidx, tbuf, part1);
        k_red1<<<RED_B, 256, 0, stream>>>(part1, partA);
        k_fin1<<<1, 256, 0, stream>>>(partA, bn1g + l * 128, bn1b + l * 128, scsh1);
        k_apply<<<G_APPLY, 256, 0, stream>>>(tbuf, scsh1, sbuf, part2);
        k_red2<<<RED_B, 128, 0, stream>>>(part2, partB);
        k_fin2<<<1, 128, 0, stream>>>(partB, bn2g + l * 64, bn2b + l * 64, scsh2);
        k_upd<<<2500, 256, 0, stream>>>(h, sbuf, scsh2);
    }
    k_pool<<<128, 256, 0, stream>>>(h, cidx, feats);
    k_head1<<<1, 128, 0, stream>>>(feats, fap, topg, topb, featsp);
    k_head2<<<128, 128, 0, stream>>>(featsp, fc2w, fc2b, fc3w, fc3b, out);
}